// Round 7
// baseline (299.410 us; speedup 1.0000x reference)
//
#include <hip/hip_runtime.h>
#include <hip/hip_bf16.h>

#define LN 96
#define BN 32
#define DM 128
#define EPN 95   // edges per receiver = L-1

typedef __attribute__((ext_vector_type(8))) short s16x8;
typedef __attribute__((ext_vector_type(4))) float f32x4;

__device__ __forceinline__ float eluf(float x){ return x > 0.f ? x : __expf(x) - 1.f; }
__device__ __forceinline__ unsigned short f2bf(float f){
    unsigned u = __float_as_uint(f);
    return (unsigned short)((u + 0x7fff + ((u >> 16) & 1)) >> 16);
}
__device__ __forceinline__ float bf2f(unsigned short h){ return __uint_as_float(((unsigned)h) << 16); }

// ---------------- weight pack: 19 slots, fragment-order bf16 hi+lo ----------------
// chunk c=(nt*4+ks)*64+lane holds 8 elems: n = nt*16+(lane&15), k = ks*32+(lane>>4)*8+e
// slots: 0..2 eW2[i]; 3 W0b; 4,5 eW1[0] S/R; 6 nW1[0]; 7 nW2[0]; 8,9 eW1[1] S/R;
//        10 nW1[1]; 11 nW2[1]; 12,13 eW1[2] S/R; 14 nW1[2]; 15 nW2[2]; 16,17 fW1 S/R;
//        18 fW2 (128x6 zero-padded to 128x16)
struct SrcTab { const float* p[19]; };

__global__ void conv_pack_kernel(SrcTab tab, unsigned short* __restrict__ hi,
                                 unsigned short* __restrict__ lo){
    int tid = blockIdx.x * 256 + threadIdx.x;   // 19*2048 = 38912
    int m = tid >> 11, c = tid & 2047;
    int l = c & 63, f = c >> 6;
    int n = (f >> 2) * 16 + (l & 15);
    int k0 = (f & 3) * 32 + (l >> 4) * 8;
    union { unsigned short us[8]; uint4 v; } ph, pl;
#pragma unroll
    for (int e = 0; e < 8; ++e){
        float x;
        if (m == 18) x = (n < 6) ? tab.p[18][(k0 + e) * 6 + n] : 0.f;
        else         x = tab.p[m][(k0 + e) * DM + n];
        unsigned short h = f2bf(x);
        ph.us[e] = h;
        pl.us[e] = f2bf(x - bf2f(h));
    }
    *(uint4*)(hi + (size_t)tid * 8) = ph.v;
    *(uint4*)(lo + (size_t)tid * 8) = pl.v;
}

__device__ __forceinline__ const s16x8* frag(const unsigned short* w, int nt, int ks, int l){
    return (const s16x8*)(w + (size_t)(((nt * 4 + ks) * 64) + l) * 8);
}

// wave-level 16-row x 16-col matmul over K=128, hi+lo weights (node path)
__device__ __forceinline__ f32x4 nmm(const char* aT, int l, int wv,
        const unsigned short* __restrict__ wh, const unsigned short* __restrict__ wl, float bias){
    const int l15 = l & 15, kgrp = l >> 4;
    const char* rb = aT + l15 * 256;
    const int swz = (l15 & 7) << 4;
    s16x8 a[4];
#pragma unroll
    for (int ks = 0; ks < 4; ++ks)
        a[ks] = *(const s16x8*)(rb + (((ks * 32 + kgrp * 8) * 2) ^ swz));
    f32x4 acc = (f32x4){bias, bias, bias, bias};
#pragma unroll
    for (int ks = 0; ks < 4; ++ks)
        acc = __builtin_amdgcn_mfma_f32_16x16x32_bf16(a[ks], *frag(wh, wv, ks, l), acc, 0, 0, 0);
#pragma unroll
    for (int ks = 0; ks < 4; ++ks)
        acc = __builtin_amdgcn_mfma_f32_16x16x32_bf16(a[ks], *frag(wl, wv, ks, l), acc, 0, 0, 0);
    return acc;
}

__device__ __forceinline__ void store_act(char* dT, int l, int wv, f32x4 acc){
    const int l15 = l & 15, kgrp = l >> 4;
    const int col = wv * 16 + l15;
#pragma unroll
    for (int i = 0; i < 4; ++i){
        int row = kgrp * 4 + i;   // C/D: col=lane&15, row=(lane>>4)*4+i
        *(unsigned short*)(dT + ((row * 256 + col * 2) ^ ((row & 7) << 4))) = f2bf(eluf(acc[i]));
    }
}

// ---------------- persistent kernel: whole network; 8 blocks per batch ----------------
__global__ __launch_bounds__(512) void gnn_persistent(
    const float* __restrict__ in,
    const float* __restrict__ W0a, const float* __restrict__ b0a, const float* __restrict__ b0b,
    const float* __restrict__ nb1, const float* __restrict__ nb2,
    const float* __restrict__ eb1, const float* __restrict__ eb2,
    const float* __restrict__ fb1, const float* __restrict__ fb2,
    const unsigned short* __restrict__ whi, const unsigned short* __restrict__ wlo,
    float* __restrict__ hsbuf, unsigned* __restrict__ ctr,
    float* __restrict__ out){

    __shared__ float hrL[12 * DM];      // own hr rows
    __shared__ float gL[12 * DM];       // own g rows (edge out / node in)
    __shared__ char actA[16 * 256];     // node A-tiles (bf16, XOR-swizzled)
    __shared__ char actB[16 * 256];
    __shared__ char tA[LN * 256];       // edge A-tiles (2 receivers in flight)
    __shared__ char tB[LN * 256];
    __shared__ float redbuf[2][6][DM];  // per-tile per-wave column partials

    const int blk = blockIdx.x;
    // XCD-aligned batch grouping: blocks {bb + 32*p} land on XCD bb%8 (round-robin heuristic)
    const int bb = blk & 31, p = blk >> 5;
    const int r0 = p * 12;              // this block's 12 node rows == its 12 receivers
    const int t = threadIdx.x;
    const int wv = t >> 6, l = t & 63;
    const int l15 = l & 15, kgrp = l >> 4;
    unsigned* ctrb = ctr + bb * 32;     // padded counter per batch

    for (int it = 0; it < 4; ++it){
        // ---------- node stage: stage A-tile (12 real rows, 4 pad) ----------
        {
            int rr = t >> 5, q = t & 31, c0 = q * 4;
            int swz = (rr & 7) << 4;
            union { unsigned short us[4]; ushort4 v; } pk;
            pk.us[0] = pk.us[1] = pk.us[2] = pk.us[3] = 0;
            if (rr < 12){
                if (it == 0){
                    int ll = r0 + rr;
                    float4 x = *(const float4*)(in + (size_t)(ll * BN + bb) * 4);
#pragma unroll
                    for (int j = 0; j < 4; ++j){
                        int c = c0 + j;
                        float a = b0a[c] + x.x * W0a[c] + x.y * W0a[DM + c]
                                + x.z * W0a[2 * DM + c] + x.w * W0a[3 * DM + c];
                        pk.us[j] = f2bf(eluf(a));
                    }
                } else {
                    float4 v = *(const float4*)(gL + rr * DM + c0);
                    pk.us[0] = f2bf(v.x); pk.us[1] = f2bf(v.y);
                    pk.us[2] = f2bf(v.z); pk.us[3] = f2bf(v.w);
                }
            }
            *(ushort4*)(actA + ((rr * 256 + c0 * 2) ^ swz)) = pk.v;
        }
        __syncthreads();

        const int sL2 = (it == 0) ? 3 : (it == 1) ? 7 : (it == 2) ? 11 : 15;
        const int sS  = (it == 0) ? 4 : (it == 1) ? 8 : (it == 2) ? 12 : 16;
        const float* bL2 = (it == 0) ? b0b : (it == 1) ? nb2 : (it == 2) ? nb2 + DM : nb2 + 2 * DM;
        const float* bP  = (it == 0) ? eb1 : (it == 1) ? eb1 + DM : (it == 2) ? eb1 + 2 * DM : fb1;

        const char* srcA;
        if (it > 0){
            const int sL1 = (it == 1) ? 6 : (it == 2) ? 10 : 14;
            const float* bL1 = (it == 1) ? nb1 : (it == 2) ? nb1 + DM : nb1 + 2 * DM;
            f32x4 acc = nmm(actA, l, wv, whi + sL1 * 16384, wlo + sL1 * 16384, bL1[wv * 16 + l15]);
            store_act(actB, l, wv, acc);
            __syncthreads();
            acc = nmm(actB, l, wv, whi + sL2 * 16384, wlo + sL2 * 16384, bL2[wv * 16 + l15]);
            store_act(actA, l, wv, acc);   // all actA reads finished before previous sync
            __syncthreads();
            srcA = actA;
        } else {
            f32x4 acc = nmm(actA, l, wv, whi + sL2 * 16384, wlo + sL2 * 16384, bL2[wv * 16 + l15]);
            store_act(actB, l, wv, acc);
            __syncthreads();
            srcA = actB;
        }

        float* hsP = hsbuf + (size_t)(it & 1) * (BN * LN * DM) + (size_t)(bb * LN) * DM;
        {
            f32x4 acc = nmm(srcA, l, wv, whi + sS * 16384, wlo + sS * 16384, 0.f);
#pragma unroll
            for (int i = 0; i < 4; ++i){
                int row = kgrp * 4 + i;
                if (row < 12) hsP[(size_t)(r0 + row) * DM + wv * 16 + l15] = acc[i];
            }
            acc = nmm(srcA, l, wv, whi + (sS + 1) * 16384, wlo + (sS + 1) * 16384, bP[wv * 16 + l15]);
#pragma unroll
            for (int i = 0; i < 4; ++i){
                int row = kgrp * 4 + i;
                if (row < 12) hrL[row * DM + wv * 16 + l15] = acc[i];
            }
        }

        // ---------- prefetch this round's post-barrier weights into regs (L2 warm) ----------
        s16x8 bfr[8][4];
        float b2v[8];
        s16x8 fh[4], fl4[4];
        float fbv = 0.f;
        if (it < 3){
            const unsigned short* wE = whi + it * 16384;
#pragma unroll
            for (int nt = 0; nt < 8; ++nt)
#pragma unroll
                for (int ks = 0; ks < 4; ++ks)
                    bfr[nt][ks] = *frag(wE, nt, ks, l);
#pragma unroll
            for (int nt = 0; nt < 8; ++nt) b2v[nt] = eb2[it * DM + nt * 16 + l15];
        } else {
#pragma unroll
            for (int ks = 0; ks < 4; ++ks){
                fh[ks]  = *frag(whi + 18 * 16384, 0, ks, l);
                fl4[ks] = *frag(wlo + 18 * 16384, 0, ks, l);
            }
            fbv = (l15 < 6) ? fb2[l15] : 0.f;
        }

        // ---------- per-batch barrier: release add; RELAXED RMW poll (no L2 inv); one acquire fence ----------
        __syncthreads();
        if (t == 0){
            __threadfence();
            __hip_atomic_fetch_add(ctrb, 1u, __ATOMIC_RELEASE, __HIP_MEMORY_SCOPE_AGENT);
            unsigned tgt = 8u * (unsigned)(it + 1);
            while (__hip_atomic_fetch_add(ctrb, 0u, __ATOMIC_RELAXED, __HIP_MEMORY_SCOPE_AGENT) < tgt)
                __builtin_amdgcn_s_sleep(8);
            __threadfence();   // single acquire-invalidate for this round
        }
        __syncthreads();

        // build 2 y1 tiles (receivers rA/rB) straight from L2/L3-resident hs
        auto buildPair = [&](int rA, int rB){
#pragma unroll
            for (int rep = 0; rep < 6; ++rep){
                int task = t + rep * 512;        // 0..3071
                int tt = task >= 1536;
                int rem = task - tt * 1536;
                int rr = rem >> 4, c0 = (rem & 15) * 8;
                int r = tt ? rB : rA;
                int r12 = r - r0;
                char* tile = tt ? tB : tA;
                int swz = (rr & 7) << 4;
                union { unsigned short us[8]; uint4 v; } pk;
                if (rr < EPN){
                    int j = rr + (rr >= r);
                    const float* hp = hsP + (size_t)j * DM + c0;
                    const float* rp = hrL + r12 * DM + c0;
                    f32x4 h0 = *(const f32x4*)hp, h1 = *(const f32x4*)(hp + 4);
                    f32x4 v0 = *(const f32x4*)rp, v1 = *(const f32x4*)(rp + 4);
#pragma unroll
                    for (int e = 0; e < 4; ++e){
                        pk.us[e]     = f2bf(eluf(h0[e] + v0[e]));
                        pk.us[e + 4] = f2bf(eluf(h1[e] + v1[e]));
                    }
                } else pk.v = make_uint4(0, 0, 0, 0);
                *(uint4*)(tile + ((rr * 256 + c0 * 2) ^ swz)) = pk.v;
            }
        };

        if (it < 3){
            // ---------- edge stage: m-split (wave owns 16 rows x all 128 cols) ----------
            for (int pr = 0; pr < 6; ++pr){
                int rA = r0 + pr * 2, rB = rA + 1;
                buildPair(rA, rB);
                __syncthreads();
                if (wv < 6){
#pragma unroll
                    for (int slot = 0; slot < 2; ++slot){
                        const char* tile = slot ? tB : tA;
                        int arow = wv * 16 + l15;
                        const char* rb = tile + arow * 256;
                        int swz = (arow & 7) << 4;
                        s16x8 a[4];
#pragma unroll
                        for (int ks = 0; ks < 4; ++ks)
                            a[ks] = *(const s16x8*)(rb + (((ks * 32 + kgrp * 8) * 2) ^ swz));
                        f32x4 acc[8] = {};
#pragma unroll
                        for (int nt = 0; nt < 8; ++nt)
#pragma unroll
                            for (int ks = 0; ks < 4; ++ks)
                                acc[nt] = __builtin_amdgcn_mfma_f32_16x16x32_bf16(a[ks], bfr[nt][ks], acc[nt], 0, 0, 0);
                        // column partial sums for this wave's 16 rows
#pragma unroll
                        for (int nt = 0; nt < 8; ++nt){
                            float cs = 0.f;
#pragma unroll
                            for (int i = 0; i < 4; ++i){
                                int row = wv * 16 + kgrp * 4 + i;
                                if (row < EPN) cs += eluf(acc[nt][i] + b2v[nt]);
                            }
                            cs += __shfl_xor(cs, 16); cs += __shfl_xor(cs, 32);
                            if (l < 16) redbuf[slot][wv][nt * 16 + l] = cs;
                        }
                    }
                }
                __syncthreads();
                if (t < 256){
                    int slot = t >> 7, col = t & 127;
                    float s = 0.f;
#pragma unroll
                    for (int v = 0; v < 6; ++v) s += redbuf[slot][v][col];
                    gL[(pr * 2 + slot) * DM + col] = s * (1.f / 95.f);
                }
            }
            __syncthreads();   // gL ready for next node stage
        } else {
            // ---------- final stage: fW2 (padded N=16), hi+lo ----------
            for (int pr = 0; pr < 6; ++pr){
                int rA = r0 + pr * 2, rB = rA + 1;
                buildPair(rA, rB);
                __syncthreads();
                // 12 (tile, mt) tasks over 8 waves
                for (int q = wv; q < 12; q += 8){
                    int tt = q >= 6;
                    int mt = q - tt * 6;
                    const char* tile = tt ? tB : tA;
                    int r = tt ? rB : rA;
                    int arow = mt * 16 + l15;
                    const char* rb = tile + arow * 256;
                    int swz = (arow & 7) << 4;
                    s16x8 a[4];
#pragma unroll
                    for (int ks = 0; ks < 4; ++ks)
                        a[ks] = *(const s16x8*)(rb + (((ks * 32 + kgrp * 8) * 2) ^ swz));
                    f32x4 acc = (f32x4){fbv, fbv, fbv, fbv};
#pragma unroll
                    for (int ks = 0; ks < 4; ++ks)
                        acc = __builtin_amdgcn_mfma_f32_16x16x32_bf16(a[ks], fh[ks], acc, 0, 0, 0);
#pragma unroll
                    for (int ks = 0; ks < 4; ++ks)
                        acc = __builtin_amdgcn_mfma_f32_16x16x32_bf16(a[ks], fl4[ks], acc, 0, 0, 0);
                    if (l15 < 6){
                        float* ob = out + ((size_t)bb * (LN * EPN) + (size_t)r * EPN) * 6;
#pragma unroll
                        for (int i = 0; i < 4; ++i){
                            int row = mt * 16 + kgrp * 4 + i;
                            if (row < EPN) ob[(size_t)row * 6 + l15] = acc[i];
                        }
                    }
                }
                __syncthreads();
            }
        }
    }
}

extern "C" void kernel_launch(void* const* d_in, const int* in_sizes, int n_in,
                              void* d_out, int out_size, void* d_ws, size_t ws_size,
                              hipStream_t stream) {
    const float* inputs = (const float*)d_in[0];
    const float* W0a = (const float*)d_in[3];
    const float* b0a = (const float*)d_in[4];
    const float* W0b = (const float*)d_in[5];
    const float* b0b = (const float*)d_in[6];
    const float* eW1 = (const float*)d_in[7];
    const float* eb1 = (const float*)d_in[8];
    const float* eW2 = (const float*)d_in[9];
    const float* eb2 = (const float*)d_in[10];
    const float* nW1 = (const float*)d_in[11];
    const float* nb1 = (const float*)d_in[12];
    const float* nW2 = (const float*)d_in[13];
    const float* nb2 = (const float*)d_in[14];
    const float* fW1 = (const float*)d_in[15];
    const float* fb1 = (const float*)d_in[16];
    const float* fW2 = (const float*)d_in[17];
    const float* fb2 = (const float*)d_in[18];
    float* out = (float*)d_out;

    unsigned short* whi = (unsigned short*)d_ws;            // 19 x 16384 bf16 hi
    unsigned short* wlo = whi + 19 * 16384;                 // 19 x 16384 bf16 lo
    float* hsbuf = (float*)(wlo + 19 * 16384);              // 2 x (32*96*128) f32 (round parity)
    unsigned* ctr = (unsigned*)(hsbuf + 2 * BN * LN * DM);  // 32 batches x 32 u32 (padded)

    SrcTab tab;
    tab.p[0] = eW2;          tab.p[1] = eW2 + 16384;  tab.p[2] = eW2 + 32768;
    tab.p[3] = W0b;
    tab.p[4] = eW1;          tab.p[5] = eW1 + 16384;
    tab.p[6] = nW1;          tab.p[7] = nW2;          tab.p[8] = eW1 + 32768;  tab.p[9]  = eW1 + 49152;
    tab.p[10] = nW1 + 16384; tab.p[11] = nW2 + 16384; tab.p[12] = eW1 + 65536; tab.p[13] = eW1 + 81920;
    tab.p[14] = nW1 + 32768; tab.p[15] = nW2 + 32768; tab.p[16] = fW1;         tab.p[17] = fW1 + 16384;
    tab.p[18] = fW2;

    hipMemsetAsync(ctr, 0, 32 * 32 * sizeof(unsigned), stream);
    conv_pack_kernel<<<152, 256, 0, stream>>>(tab, whi, wlo);
    gnn_persistent<<<256, 512, 0, stream>>>(inputs, W0a, b0a, b0b, nb1, nb2, eb1, eb2, fb1, fb2,
                                            whi, wlo, hsbuf, ctr, out);
}

// Round 8
// 142.107 us; speedup vs baseline: 2.1069x; 2.1069x over previous
//
#include <hip/hip_runtime.h>
#include <hip/hip_bf16.h>

#define LN 96
#define BN 32
#define DM 128
#define EPN 95   // edges per receiver = L-1

typedef __attribute__((ext_vector_type(8))) short s16x8;
typedef __attribute__((ext_vector_type(4))) float f32x4;

__device__ __forceinline__ float eluf(float x){ return x > 0.f ? x : __expf(x) - 1.f; }
__device__ __forceinline__ unsigned short f2bf(float f){
    unsigned u = __float_as_uint(f);
    return (unsigned short)((u + 0x7fff + ((u >> 16) & 1)) >> 16);
}
__device__ __forceinline__ float bf2f(unsigned short h){ return __uint_as_float(((unsigned)h) << 16); }

// ---------------- weight pack: 19 slots, fragment-order bf16 hi+lo ----------------
// chunk c=(nt*4+ks)*64+lane holds 8 elems: n = nt*16+(lane&15), k = ks*32+(lane>>4)*8+e
// slots: 0..2 eW2[i]; 3 W0b; 4,5 eW1[0] S/R; 6 nW1[0]; 7 nW2[0]; 8,9 eW1[1] S/R;
//        10 nW1[1]; 11 nW2[1]; 12,13 eW1[2] S/R; 14 nW1[2]; 15 nW2[2]; 16,17 fW1 S/R;
//        18 fW2 (unused; final stays f32 scalar)
struct SrcTab { const float* p[19]; };

__global__ void conv_pack_kernel(SrcTab tab, unsigned short* __restrict__ hi,
                                 unsigned short* __restrict__ lo){
    int tid = blockIdx.x * 256 + threadIdx.x;   // 19*2048 = 38912
    int m = tid >> 11, c = tid & 2047;
    int l = c & 63, f = c >> 6;
    int n = (f >> 2) * 16 + (l & 15);
    int k0 = (f & 3) * 32 + (l >> 4) * 8;
    union { unsigned short us[8]; uint4 v; } ph, pl;
#pragma unroll
    for (int e = 0; e < 8; ++e){
        float x;
        if (m == 18) x = (n < 6) ? tab.p[18][(k0 + e) * 6 + n] : 0.f;
        else         x = tab.p[m][(k0 + e) * DM + n];
        unsigned short h = f2bf(x);
        ph.us[e] = h;
        pl.us[e] = f2bf(x - bf2f(h));
    }
    *(uint4*)(hi + (size_t)tid * 8) = ph.v;
    *(uint4*)(lo + (size_t)tid * 8) = pl.v;
}

// ---------------- wave-level 16x32 matmul step (2 n-tiles per wave, hi+lo) ----------------
__device__ __forceinline__ void mmw(const char* atile, int l,
                                    const unsigned short* __restrict__ whW,
                                    const unsigned short* __restrict__ wlW,
                                    f32x4 acc[2]) {
    const int l15 = l & 15, kgrp = l >> 4;
    s16x8 a[4];
#pragma unroll
    for (int ks = 0; ks < 4; ++ks)
        a[ks] = *(const s16x8*)(atile + ((l15 * 256 + (ks * 32 + kgrp * 8) * 2) ^ ((l15 & 7) << 4)));
#pragma unroll
    for (int ntl = 0; ntl < 2; ++ntl) {
#pragma unroll
        for (int ks = 0; ks < 4; ++ks) {
            s16x8 bh = *(const s16x8*)(whW + (size_t)((ntl * 4 + ks) * 64 + l) * 8);
            acc[ntl] = __builtin_amdgcn_mfma_f32_16x16x32_bf16(a[ks], bh, acc[ntl], 0, 0, 0);
        }
#pragma unroll
        for (int ks = 0; ks < 4; ++ks) {
            s16x8 bl = *(const s16x8*)(wlW + (size_t)((ntl * 4 + ks) * 64 + l) * 8);
            acc[ntl] = __builtin_amdgcn_mfma_f32_16x16x32_bf16(a[ks], bl, acc[ntl], 0, 0, 0);
        }
    }
}

__device__ __forceinline__ void store_act(char* atile, int l, int w, f32x4 acc[2]) {
    const int l15 = l & 15, kgrp = l >> 4;
#pragma unroll
    for (int ntl = 0; ntl < 2; ++ntl)
#pragma unroll
        for (int i = 0; i < 4; ++i) {
            int row = kgrp * 4 + i;              // C/D: col=lane&15, row=(lane>>4)*4+i
            int col = (2 * w + ntl) * 16 + l15;
            *(unsigned short*)(atile + ((row * 256 + col * 2) ^ ((row & 7) << 4))) = f2bf(eluf(acc[ntl][i]));
        }
}

// ---------------- node0: input MLP (scalar W0a, MFMA W0b) + proj eW1[0] ----------------
// 192 blocks x 256 thr; 16 rows/block; wave w owns n-cols [w*32, w*32+32).  (R3-proven)
__global__ __launch_bounds__(256) void node0_kernel(
    const float* __restrict__ in,
    const float* __restrict__ W0a, const float* __restrict__ b0a,
    const unsigned short* __restrict__ w2h, const unsigned short* __restrict__ w2l,
    const float* __restrict__ b2,
    const unsigned short* __restrict__ wsh, const unsigned short* __restrict__ wsl,
    const unsigned short* __restrict__ wrh, const unsigned short* __restrict__ wrl,
    const float* __restrict__ bp,
    float* __restrict__ hs, float* __restrict__ hr) {
    __shared__ char atile[16 * 256];
    const int t = threadIdx.x;
    const int row0 = blockIdx.x * 16;
    const int l = t & 63, w = t >> 6;
    const int l15 = l & 15, kgrp = l >> 4;

    {   // fused scalar K=4 layer (W0a) -> bf16 tile
        int rr = t >> 4, q = t & 15, c0 = q * 8;
        int swz = (rr & 7) << 4;
        union { unsigned short us[8]; uint4 v; } pk;
        int row = row0 + rr;
        int b = row / LN, ll = row - b * LN;
        float4 x = *(const float4*)(in + (size_t)(ll * BN + b) * 4);
#pragma unroll
        for (int j = 0; j < 8; ++j) {
            int cc = c0 + j;
            float a = b0a[cc] + x.x * W0a[cc] + x.y * W0a[DM + cc]
                    + x.z * W0a[2 * DM + cc] + x.w * W0a[3 * DM + cc];
            pk.us[j] = f2bf(eluf(a));
        }
        *(uint4*)(atile + ((rr * 256 + c0 * 2) ^ swz)) = pk.v;
    }
    __syncthreads();

    f32x4 acc[2];
    const int cA = (2 * w) * 16 + l15, cB = (2 * w + 1) * 16 + l15;
    {   // layer W0b
        float ba = b2[cA], bb = b2[cB];
        acc[0] = (f32x4){ba, ba, ba, ba};
        acc[1] = (f32x4){bb, bb, bb, bb};
        mmw(atile, l, w2h + w * 4096, w2l + w * 4096, acc);
        __syncthreads();
        store_act(atile, l, w, acc);
        __syncthreads();
    }
    // projection S
    acc[0] = (f32x4){0.f, 0.f, 0.f, 0.f};
    acc[1] = (f32x4){0.f, 0.f, 0.f, 0.f};
    mmw(atile, l, wsh + w * 4096, wsl + w * 4096, acc);
#pragma unroll
    for (int ntl = 0; ntl < 2; ++ntl)
#pragma unroll
        for (int i = 0; i < 4; ++i)
            hs[(size_t)(row0 + kgrp * 4 + i) * DM + (2 * w + ntl) * 16 + l15] = acc[ntl][i];
    // projection R (+bp)
    {
        float ba = bp[cA], bb = bp[cB];
        acc[0] = (f32x4){ba, ba, ba, ba};
        acc[1] = (f32x4){bb, bb, bb, bb};
        mmw(atile, l, wrh + w * 4096, wrl + w * 4096, acc);
    }
#pragma unroll
    for (int ntl = 0; ntl < 2; ++ntl)
#pragma unroll
        for (int i = 0; i < 4; ++i)
            hr[(size_t)(row0 + kgrp * 4 + i) * DM + (2 * w + ntl) * 16 + l15] = acc[ntl][i];
}

// ---------------- fused edge+node: 768 blocks x 256 thr; block owns 4 receivers ----------------
// edge: per receiver r: y1=elu(hs[send]+hr[r]); y2=elu(y1@eW2+b2); g[r]=mean_rows(y2)  (LDS)
// node tail on the same 4 rows: act=elu(elu(g@W1+b1)@W2+b2); hsOut=act@WpS; hrOut=act@WpR+bp
__global__ __launch_bounds__(256) void edge_node_kernel(
    const float* __restrict__ hsIn, const float* __restrict__ hrIn,
    const unsigned short* __restrict__ whi, const unsigned short* __restrict__ wlo,
    int eslot, const float* __restrict__ eb2v,
    int s1, int s2, int sS,
    const float* __restrict__ b1, const float* __restrict__ b2, const float* __restrict__ bp,
    float* __restrict__ hsOut, float* __restrict__ hrOut) {
    __shared__ char y1[LN * 256];     // 96x128 bf16, XOR-swizzled
    __shared__ float hrL[4 * DM];
    __shared__ float gL[4 * DM];
    __shared__ char actA[16 * 256];
    __shared__ char actB[16 * 256];
    const int blk = blockIdx.x;
    const int b = blk / 24, r0 = (blk % 24) * 4;
    const int t = threadIdx.x;
    const int w = t >> 6, l = t & 63;
    const int l15 = l & 15, kgrp = l >> 4;

    if (t < 128) {
        int rr = t >> 5, c4 = (t & 31) * 4;
        *(float4*)(hrL + rr * DM + c4) = *(const float4*)(hrIn + ((size_t)(b * LN + r0 + rr)) * DM + c4);
    }
    // edge B-frags (hi only), wave n-split
    s16x8 bfr[2][4];
#pragma unroll
    for (int ntl = 0; ntl < 2; ++ntl)
#pragma unroll
        for (int ks = 0; ks < 4; ++ks)
            bfr[ntl][ks] = *(const s16x8*)(whi + (size_t)eslot * 16384 +
                           (size_t)(((2 * w + ntl) * 4 + ks) * 64 + l) * 8);
    float b20 = eb2v[(2 * w) * 16 + l15], b21 = eb2v[(2 * w + 1) * 16 + l15];
    __syncthreads();

    const float* hsB = hsIn + (size_t)(b * LN) * DM;
    for (int rr4 = 0; rr4 < 4; ++rr4) {
        int r = r0 + rr4;
        // build y1: 1536 tasks (96 rows x 16 col-chunks of 8)
#pragma unroll
        for (int rep = 0; rep < 6; ++rep) {
            int task = t + rep * 256;
            int rr = task >> 4, c0 = (task & 15) * 8;
            int swz = (rr & 7) << 4;
            union { unsigned short us[8]; uint4 v; } pk;
            if (rr < EPN) {
                int j = rr + (rr >= r);
                const float* hp = hsB + (size_t)j * DM + c0;
                const float* rp = hrL + rr4 * DM + c0;
                f32x4 h0 = *(const f32x4*)hp, h1 = *(const f32x4*)(hp + 4);
                f32x4 v0 = *(const f32x4*)rp, v1 = *(const f32x4*)(rp + 4);
#pragma unroll
                for (int e = 0; e < 4; ++e) {
                    pk.us[e]     = f2bf(eluf(h0[e] + v0[e]));
                    pk.us[e + 4] = f2bf(eluf(h1[e] + v1[e]));
                }
            } else pk.v = make_uint4(0, 0, 0, 0);
            *(uint4*)(y1 + ((rr * 256 + c0 * 2) ^ swz)) = pk.v;
        }
        __syncthreads();
        // MFMA + epilogue (n-split: wave owns 32 cols)
        f32x4 acc[6][2] = {};
#pragma unroll
        for (int mt = 0; mt < 6; ++mt) {
            int arow = mt * 16 + l15;
            const char* rb = y1 + arow * 256;
            int swz = (arow & 7) << 4;
#pragma unroll
            for (int ks = 0; ks < 4; ++ks) {
                s16x8 a = *(const s16x8*)(rb + (((ks * 32 + kgrp * 8) * 2) ^ swz));
                acc[mt][0] = __builtin_amdgcn_mfma_f32_16x16x32_bf16(a, bfr[0][ks], acc[mt][0], 0, 0, 0);
                acc[mt][1] = __builtin_amdgcn_mfma_f32_16x16x32_bf16(a, bfr[1][ks], acc[mt][1], 0, 0, 0);
            }
        }
        float cs0 = 0.f, cs1 = 0.f;
#pragma unroll
        for (int mt = 0; mt < 6; ++mt)
#pragma unroll
            for (int i = 0; i < 4; ++i) {
                int row = mt * 16 + kgrp * 4 + i;
                if (row < EPN) {
                    cs0 += eluf(acc[mt][0][i] + b20);
                    cs1 += eluf(acc[mt][1][i] + b21);
                }
            }
        cs0 += __shfl_xor(cs0, 16); cs0 += __shfl_xor(cs0, 32);
        cs1 += __shfl_xor(cs1, 16); cs1 += __shfl_xor(cs1, 32);
        if (l < 16) {
            gL[rr4 * DM + (2 * w) * 16 + l]       = cs0 * (1.f / 95.f);
            gL[rr4 * DM + (2 * w + 1) * 16 + l]   = cs1 * (1.f / 95.f);
        }
        __syncthreads();   // y1 safe to overwrite; gL complete at loop end
    }

    // ---------- node tail on the 4 g rows ----------
    {
        int rr = t >> 4, q = t & 15, c0 = q * 8;
        int swz = (rr & 7) << 4;
        union { unsigned short us[8]; uint4 v; } pk;
        if (rr < 4) {
            const float* src = gL + rr * DM + c0;
            float4 f0 = *(const float4*)(src);
            float4 f1 = *(const float4*)(src + 4);
            pk.us[0] = f2bf(f0.x); pk.us[1] = f2bf(f0.y); pk.us[2] = f2bf(f0.z); pk.us[3] = f2bf(f0.w);
            pk.us[4] = f2bf(f1.x); pk.us[5] = f2bf(f1.y); pk.us[6] = f2bf(f1.z); pk.us[7] = f2bf(f1.w);
        } else pk.v = make_uint4(0, 0, 0, 0);
        *(uint4*)(actA + ((rr * 256 + c0 * 2) ^ swz)) = pk.v;
    }
    __syncthreads();

    f32x4 acc[2];
    const int cA = (2 * w) * 16 + l15, cB = (2 * w + 1) * 16 + l15;
    {   // layer 1
        float ba = b1[cA], bb = b1[cB];
        acc[0] = (f32x4){ba, ba, ba, ba};
        acc[1] = (f32x4){bb, bb, bb, bb};
        mmw(actA, l, whi + (size_t)s1 * 16384 + w * 4096, wlo + (size_t)s1 * 16384 + w * 4096, acc);
        __syncthreads();
        store_act(actB, l, w, acc);
        __syncthreads();
    }
    {   // layer 2
        float ba = b2[cA], bb = b2[cB];
        acc[0] = (f32x4){ba, ba, ba, ba};
        acc[1] = (f32x4){bb, bb, bb, bb};
        mmw(actB, l, whi + (size_t)s2 * 16384 + w * 4096, wlo + (size_t)s2 * 16384 + w * 4096, acc);
        __syncthreads();
        store_act(actA, l, w, acc);
        __syncthreads();
    }
    // projection S
    acc[0] = (f32x4){0.f, 0.f, 0.f, 0.f};
    acc[1] = (f32x4){0.f, 0.f, 0.f, 0.f};
    mmw(actA, l, whi + (size_t)sS * 16384 + w * 4096, wlo + (size_t)sS * 16384 + w * 4096, acc);
#pragma unroll
    for (int ntl = 0; ntl < 2; ++ntl)
#pragma unroll
        for (int i = 0; i < 4; ++i) {
            int row = kgrp * 4 + i;
            if (row < 4)
                hsOut[(size_t)(b * LN + r0 + row) * DM + (2 * w + ntl) * 16 + l15] = acc[ntl][i];
        }
    // projection R (+bp)
    {
        float ba = bp[cA], bb = bp[cB];
        acc[0] = (f32x4){ba, ba, ba, ba};
        acc[1] = (f32x4){bb, bb, bb, bb};
        mmw(actA, l, whi + (size_t)(sS + 1) * 16384 + w * 4096, wlo + (size_t)(sS + 1) * 16384 + w * 4096, acc);
    }
#pragma unroll
    for (int ntl = 0; ntl < 2; ++ntl)
#pragma unroll
        for (int i = 0; i < 4; ++i) {
            int row = kgrp * 4 + i;
            if (row < 4)
                hrOut[(size_t)(b * LN + r0 + row) * DM + (2 * w + ntl) * 16 + l15] = acc[ntl][i];
        }
}

// ---------------- final: out[b][e][c] = elu(hs_f[send]+hr_f[recv]) @ fW2 + fb2 (f32 scalar) ----
__global__ void final_kernel(const float* __restrict__ hs, const float* __restrict__ hr,
                             const float* __restrict__ fW2, const float* __restrict__ fb2,
                             float* __restrict__ out) {
    __shared__ float w2l[DM * 6];
    __shared__ float hrbuf[DM];
    const int r = blockIdx.x, b = blockIdx.y;
    const int t = threadIdx.x;   // 128 threads
    hrbuf[t] = hr[((size_t)b * LN + r) * DM + t];
    for (int c = 0; c < 6; ++c) w2l[t * 6 + c] = fW2[t * 6 + c];
    __syncthreads();
    int k = t;
    if (k < EPN) {
        int j = k + (k >= r);
        const float* src = hs + ((size_t)b * LN + j) * DM;
        float acc[6];
        for (int c = 0; c < 6; ++c) acc[c] = fb2[c];
        for (int d0 = 0; d0 < DM; d0 += 4) {
            float4 f = *(const float4*)(src + d0);
            float v0 = eluf(f.x + hrbuf[d0 + 0]);
            float v1 = eluf(f.y + hrbuf[d0 + 1]);
            float v2 = eluf(f.z + hrbuf[d0 + 2]);
            float v3 = eluf(f.w + hrbuf[d0 + 3]);
            for (int c = 0; c < 6; ++c)
                acc[c] += v0 * w2l[(d0 + 0) * 6 + c] + v1 * w2l[(d0 + 1) * 6 + c]
                        + v2 * w2l[(d0 + 2) * 6 + c] + v3 * w2l[(d0 + 3) * 6 + c];
        }
        float* o = out + (((size_t)b * (LN * EPN)) + r * EPN + k) * 6;
        for (int c = 0; c < 6; ++c) o[c] = acc[c];
    }
}

extern "C" void kernel_launch(void* const* d_in, const int* in_sizes, int n_in,
                              void* d_out, int out_size, void* d_ws, size_t ws_size,
                              hipStream_t stream) {
    const float* inputs = (const float*)d_in[0];
    const float* W0a = (const float*)d_in[3];
    const float* b0a = (const float*)d_in[4];
    const float* W0b = (const float*)d_in[5];
    const float* b0b = (const float*)d_in[6];
    const float* eW1 = (const float*)d_in[7];
    const float* eb1 = (const float*)d_in[8];
    const float* eW2 = (const float*)d_in[9];
    const float* eb2 = (const float*)d_in[10];
    const float* nW1 = (const float*)d_in[11];
    const float* nb1 = (const float*)d_in[12];
    const float* nW2 = (const float*)d_in[13];
    const float* nb2 = (const float*)d_in[14];
    const float* fW1 = (const float*)d_in[15];
    const float* fb1 = (const float*)d_in[16];
    const float* fW2 = (const float*)d_in[17];
    const float* fb2 = (const float*)d_in[18];
    float* out = (float*)d_out;

    const int NR = BN * LN;                                 // 3072 node rows
    unsigned short* whi = (unsigned short*)d_ws;            // 19 x 16384 bf16 hi
    unsigned short* wlo = whi + 19 * 16384;                 // 19 x 16384 bf16 lo
    float* hsA = (float*)(wlo + 19 * 16384);
    float* hrA = hsA + NR * DM;
    float* hsB = hrA + NR * DM;
    float* hrB = hsB + NR * DM;

    SrcTab tab;
    tab.p[0] = eW2;          tab.p[1] = eW2 + 16384;  tab.p[2] = eW2 + 32768;
    tab.p[3] = W0b;
    tab.p[4] = eW1;          tab.p[5] = eW1 + 16384;
    tab.p[6] = nW1;          tab.p[7] = nW2;          tab.p[8] = eW1 + 32768;  tab.p[9]  = eW1 + 49152;
    tab.p[10] = nW1 + 16384; tab.p[11] = nW2 + 16384; tab.p[12] = eW1 + 65536; tab.p[13] = eW1 + 81920;
    tab.p[14] = nW1 + 32768; tab.p[15] = nW2 + 32768; tab.p[16] = fW1;         tab.p[17] = fW1 + 16384;
    tab.p[18] = fW2;

    #define WM(m) (whi + (m) * 16384), (wlo + (m) * 16384)

    conv_pack_kernel<<<152, 256, 0, stream>>>(tab, whi, wlo);
    // round 0: input MLP + proj eW1[0]
    node0_kernel<<<192, 256, 0, stream>>>(inputs, W0a, b0a, WM(3), b0b, WM(4), WM(5), eb1, hsA, hrA);
    // fused rounds: edge(eW2[i]) + node MLP(i+1 weights) + proj
    edge_node_kernel<<<768, 256, 0, stream>>>(hsA, hrA, whi, wlo, 0, eb2,
                                              6, 7, 8, nb1, nb2, eb1 + DM, hsB, hrB);
    edge_node_kernel<<<768, 256, 0, stream>>>(hsB, hrB, whi, wlo, 1, eb2 + DM,
                                              10, 11, 12, nb1 + DM, nb2 + DM, eb1 + 2 * DM, hsA, hrA);
    edge_node_kernel<<<768, 256, 0, stream>>>(hsA, hrA, whi, wlo, 2, eb2 + 2 * DM,
                                              14, 15, 16, nb1 + 2 * DM, nb2 + 2 * DM, fb1, hsB, hrB);
    // final: fW2 (f32 scalar)
    final_kernel<<<dim3(LN, BN), 128, 0, stream>>>(hsB, hrB, fW2, fb2, out);
    #undef WM
}

// Round 9
// 137.968 us; speedup vs baseline: 2.1701x; 1.0300x over previous
//
#include <hip/hip_runtime.h>
#include <hip/hip_bf16.h>

#define LN 96
#define BN 32
#define DM 128
#define EPN 95   // edges per receiver = L-1

typedef __attribute__((ext_vector_type(8))) short s16x8;
typedef __attribute__((ext_vector_type(4))) float f32x4;

__device__ __forceinline__ float eluf(float x){ return x > 0.f ? x : __expf(x) - 1.f; }
__device__ __forceinline__ unsigned short f2bf(float f){
    unsigned u = __float_as_uint(f);
    return (unsigned short)((u + 0x7fff + ((u >> 16) & 1)) >> 16);
}
__device__ __forceinline__ float bf2f(unsigned short h){ return __uint_as_float(((unsigned)h) << 16); }
// packed RNE f32->bf16 pair (1 instruction): D[15:0]=bf16(lo), D[31:16]=bf16(hi)
__device__ __forceinline__ unsigned cvtpk(float lo, float hi){
    unsigned r;
    asm("v_cvt_pk_bf16_f32 %0, %1, %2" : "=v"(r) : "v"(lo), "v"(hi));
    return r;
}

// ---------------- weight pack: 19 slots, fragment-order bf16 hi+lo ----------------
// chunk c=(nt*4+ks)*64+lane holds 8 elems: n = nt*16+(lane&15), k = ks*32+(lane>>4)*8+e
// slots: 0..2 eW2[i]; 3 W0b; 4,5 eW1[0] S/R; 6 nW1[0]; 7 nW2[0]; 8,9 eW1[1] S/R;
//        10 nW1[1]; 11 nW2[1]; 12,13 eW1[2] S/R; 14 nW1[2]; 15 nW2[2]; 16,17 fW1 S/R;
//        18 fW2 (unused; final stays f32 scalar)
struct SrcTab { const float* p[19]; };

__global__ void conv_pack_kernel(SrcTab tab, unsigned short* __restrict__ hi,
                                 unsigned short* __restrict__ lo){
    int tid = blockIdx.x * 256 + threadIdx.x;   // 19*2048 = 38912
    int m = tid >> 11, c = tid & 2047;
    int l = c & 63, f = c >> 6;
    int n = (f >> 2) * 16 + (l & 15);
    int k0 = (f & 3) * 32 + (l >> 4) * 8;
    union { unsigned short us[8]; uint4 v; } ph, pl;
#pragma unroll
    for (int e = 0; e < 8; ++e){
        float x;
        if (m == 18) x = (n < 6) ? tab.p[18][(k0 + e) * 6 + n] : 0.f;
        else         x = tab.p[m][(k0 + e) * DM + n];
        unsigned short h = f2bf(x);
        ph.us[e] = h;
        pl.us[e] = f2bf(x - bf2f(h));
    }
    *(uint4*)(hi + (size_t)tid * 8) = ph.v;
    *(uint4*)(lo + (size_t)tid * 8) = pl.v;
}

// ---------------- wave-level 16x32 matmul step (2 n-tiles per wave, hi+lo) ----------------
__device__ __forceinline__ void mmw(const char* atile, int l,
                                    const unsigned short* __restrict__ whW,
                                    const unsigned short* __restrict__ wlW,
                                    f32x4 acc[2]) {
    const int l15 = l & 15, kgrp = l >> 4;
    s16x8 a[4];
#pragma unroll
    for (int ks = 0; ks < 4; ++ks)
        a[ks] = *(const s16x8*)(atile + ((l15 * 256 + (ks * 32 + kgrp * 8) * 2) ^ ((l15 & 7) << 4)));
#pragma unroll
    for (int ntl = 0; ntl < 2; ++ntl) {
#pragma unroll
        for (int ks = 0; ks < 4; ++ks) {
            s16x8 bh = *(const s16x8*)(whW + (size_t)((ntl * 4 + ks) * 64 + l) * 8);
            acc[ntl] = __builtin_amdgcn_mfma_f32_16x16x32_bf16(a[ks], bh, acc[ntl], 0, 0, 0);
        }
#pragma unroll
        for (int ks = 0; ks < 4; ++ks) {
            s16x8 bl = *(const s16x8*)(wlW + (size_t)((ntl * 4 + ks) * 64 + l) * 8);
            acc[ntl] = __builtin_amdgcn_mfma_f32_16x16x32_bf16(a[ks], bl, acc[ntl], 0, 0, 0);
        }
    }
}

__device__ __forceinline__ void store_act(char* atile, int l, int w, f32x4 acc[2]) {
    const int l15 = l & 15, kgrp = l >> 4;
#pragma unroll
    for (int ntl = 0; ntl < 2; ++ntl)
#pragma unroll
        for (int i = 0; i < 4; ++i) {
            int row = kgrp * 4 + i;              // C/D: col=lane&15, row=(lane>>4)*4+i
            int col = (2 * w + ntl) * 16 + l15;
            *(unsigned short*)(atile + ((row * 256 + col * 2) ^ ((row & 7) << 4))) = f2bf(eluf(acc[ntl][i]));
        }
}

// ---------------- node0: input MLP (scalar W0a, MFMA W0b) + proj eW1[0] ----------------
// 192 blocks x 256 thr; 16 rows/block; XCD-aligned: blk = q*32 + b (batch in low 5 bits)
__global__ __launch_bounds__(256) void node0_kernel(
    const float* __restrict__ in,
    const float* __restrict__ W0a, const float* __restrict__ b0a,
    const unsigned short* __restrict__ w2h, const unsigned short* __restrict__ w2l,
    const float* __restrict__ b2,
    const unsigned short* __restrict__ wsh, const unsigned short* __restrict__ wsl,
    const unsigned short* __restrict__ wrh, const unsigned short* __restrict__ wrl,
    const float* __restrict__ bp,
    float* __restrict__ hs, float* __restrict__ hr) {
    __shared__ char atile[16 * 256];
    const int t = threadIdx.x;
    const int q = blockIdx.x >> 5, bblk = blockIdx.x & 31;
    const int row0 = bblk * LN + q * 16;
    const int l = t & 63, w = t >> 6;
    const int l15 = l & 15, kgrp = l >> 4;

    {   // fused scalar K=4 layer (W0a) -> bf16 tile
        int rr = t >> 4, qq = t & 15, c0 = qq * 8;
        int swz = (rr & 7) << 4;
        union { unsigned short us[8]; uint4 v; } pk;
        int row = row0 + rr;
        int b = row / LN, ll = row - b * LN;
        float4 x = *(const float4*)(in + (size_t)(ll * BN + b) * 4);
#pragma unroll
        for (int j = 0; j < 8; ++j) {
            int cc = c0 + j;
            float a = b0a[cc] + x.x * W0a[cc] + x.y * W0a[DM + cc]
                    + x.z * W0a[2 * DM + cc] + x.w * W0a[3 * DM + cc];
            pk.us[j] = f2bf(eluf(a));
        }
        *(uint4*)(atile + ((rr * 256 + c0 * 2) ^ swz)) = pk.v;
    }
    __syncthreads();

    f32x4 acc[2];
    const int cA = (2 * w) * 16 + l15, cB = (2 * w + 1) * 16 + l15;
    {   // layer W0b
        float ba = b2[cA], bb = b2[cB];
        acc[0] = (f32x4){ba, ba, ba, ba};
        acc[1] = (f32x4){bb, bb, bb, bb};
        mmw(atile, l, w2h + w * 4096, w2l + w * 4096, acc);
        __syncthreads();
        store_act(atile, l, w, acc);
        __syncthreads();
    }
    // projection S
    acc[0] = (f32x4){0.f, 0.f, 0.f, 0.f};
    acc[1] = (f32x4){0.f, 0.f, 0.f, 0.f};
    mmw(atile, l, wsh + w * 4096, wsl + w * 4096, acc);
#pragma unroll
    for (int ntl = 0; ntl < 2; ++ntl)
#pragma unroll
        for (int i = 0; i < 4; ++i)
            hs[(size_t)(row0 + kgrp * 4 + i) * DM + (2 * w + ntl) * 16 + l15] = acc[ntl][i];
    // projection R (+bp)
    {
        float ba = bp[cA], bb = bp[cB];
        acc[0] = (f32x4){ba, ba, ba, ba};
        acc[1] = (f32x4){bb, bb, bb, bb};
        mmw(atile, l, wrh + w * 4096, wrl + w * 4096, acc);
    }
#pragma unroll
    for (int ntl = 0; ntl < 2; ++ntl)
#pragma unroll
        for (int i = 0; i < 4; ++i)
            hr[(size_t)(row0 + kgrp * 4 + i) * DM + (2 * w + ntl) * 16 + l15] = acc[ntl][i];
}

// ---------------- fused edge+node: 1024 blocks x 256 thr; block owns 3 receivers ----------------
// XCD-aligned: blk = rg*32 + b -> blk%8 = b%8 (batch's producers and consumers share one XCD L2)
__global__ __launch_bounds__(256) void edge_node_kernel(
    const float* __restrict__ hsIn, const float* __restrict__ hrIn,
    const unsigned short* __restrict__ whi, const unsigned short* __restrict__ wlo,
    int eslot, const float* __restrict__ eb2v,
    int s1, int s2, int sS,
    const float* __restrict__ b1, const float* __restrict__ b2, const float* __restrict__ bp,
    float* __restrict__ hsOut, float* __restrict__ hrOut) {
    __shared__ char y1[LN * 256];     // 96x128 bf16, XOR-swizzled
    __shared__ float hrL[3 * DM];
    __shared__ float gL[3 * DM];
    __shared__ char actA[16 * 256];
    __shared__ char actB[16 * 256];
    const int blk = blockIdx.x;
    const int rg = blk >> 5, b = blk & 31;
    const int r0 = rg * 3;
    const int t = threadIdx.x;
    const int w = t >> 6, l = t & 63;
    const int l15 = l & 15, kgrp = l >> 4;

    if (t < 96) {
        int rr = t >> 5, c4 = (t & 31) * 4;
        *(float4*)(hrL + rr * DM + c4) = *(const float4*)(hrIn + ((size_t)(b * LN + r0 + rr)) * DM + c4);
    }
    // edge B-frags (hi only), wave n-split
    s16x8 bfr[2][4];
#pragma unroll
    for (int ntl = 0; ntl < 2; ++ntl)
#pragma unroll
        for (int ks = 0; ks < 4; ++ks)
            bfr[ntl][ks] = *(const s16x8*)(whi + (size_t)eslot * 16384 +
                           (size_t)(((2 * w + ntl) * 4 + ks) * 64 + l) * 8);
    float b20 = eb2v[(2 * w) * 16 + l15], b21 = eb2v[(2 * w + 1) * 16 + l15];
    __syncthreads();

    const float* hsB = hsIn + (size_t)(b * LN) * DM;
    for (int rr3 = 0; rr3 < 3; ++rr3) {
        int r = r0 + rr3;
        // build y1: 1536 tasks; 3 chunks of 2 reps with hoisted global loads
#pragma unroll
        for (int ch = 0; ch < 3; ++ch) {
            float4 h0[2], h1[2];
            int rrs[2], c0s[2];
#pragma unroll
            for (int k = 0; k < 2; ++k) {
                int task = t + (ch * 2 + k) * 256;
                int rr = task >> 4, c0 = (task & 15) * 8;
                rrs[k] = rr; c0s[k] = c0;
                if (rr < EPN) {
                    int j = rr + (rr >= r);
                    const float* hp = hsB + (size_t)j * DM + c0;
                    h0[k] = *(const float4*)hp;
                    h1[k] = *(const float4*)(hp + 4);
                }
            }
#pragma unroll
            for (int k = 0; k < 2; ++k) {
                int rr = rrs[k], c0 = c0s[k];
                int swz = (rr & 7) << 4;
                uint4 pk = make_uint4(0, 0, 0, 0);
                if (rr < EPN) {
                    const float* rp = hrL + rr3 * DM + c0;
                    f32x4 v0 = *(const f32x4*)rp, v1 = *(const f32x4*)(rp + 4);
                    float e0 = eluf(h0[k].x + v0[0]), e1 = eluf(h0[k].y + v0[1]);
                    float e2 = eluf(h0[k].z + v0[2]), e3 = eluf(h0[k].w + v0[3]);
                    float e4 = eluf(h1[k].x + v1[0]), e5 = eluf(h1[k].y + v1[1]);
                    float e6 = eluf(h1[k].z + v1[2]), e7 = eluf(h1[k].w + v1[3]);
                    pk.x = cvtpk(e0, e1); pk.y = cvtpk(e2, e3);
                    pk.z = cvtpk(e4, e5); pk.w = cvtpk(e6, e7);
                }
                *(uint4*)(y1 + ((rr * 256 + c0 * 2) ^ swz)) = pk;
            }
        }
        __syncthreads();
        // MFMA + epilogue (n-split: wave owns 32 cols)
        f32x4 acc[6][2] = {};
#pragma unroll
        for (int mt = 0; mt < 6; ++mt) {
            int arow = mt * 16 + l15;
            const char* rb = y1 + arow * 256;
            int swz = (arow & 7) << 4;
#pragma unroll
            for (int ks = 0; ks < 4; ++ks) {
                s16x8 a = *(const s16x8*)(rb + (((ks * 32 + kgrp * 8) * 2) ^ swz));
                acc[mt][0] = __builtin_amdgcn_mfma_f32_16x16x32_bf16(a, bfr[0][ks], acc[mt][0], 0, 0, 0);
                acc[mt][1] = __builtin_amdgcn_mfma_f32_16x16x32_bf16(a, bfr[1][ks], acc[mt][1], 0, 0, 0);
            }
        }
        float cs0 = 0.f, cs1 = 0.f;
#pragma unroll
        for (int mt = 0; mt < 6; ++mt)
#pragma unroll
            for (int i = 0; i < 4; ++i) {
                int row = mt * 16 + kgrp * 4 + i;
                if (row < EPN) {
                    cs0 += eluf(acc[mt][0][i] + b20);
                    cs1 += eluf(acc[mt][1][i] + b21);
                }
            }
        cs0 += __shfl_xor(cs0, 16); cs0 += __shfl_xor(cs0, 32);
        cs1 += __shfl_xor(cs1, 16); cs1 += __shfl_xor(cs1, 32);
        if (l < 16) {
            gL[rr3 * DM + (2 * w) * 16 + l]     = cs0 * (1.f / 95.f);
            gL[rr3 * DM + (2 * w + 1) * 16 + l] = cs1 * (1.f / 95.f);
        }
        __syncthreads();
    }

    // ---------- node tail on the 3 g rows ----------
    {
        int rr = t >> 4, q = t & 15, c0 = q * 8;
        int swz = (rr & 7) << 4;
        union { unsigned short us[8]; uint4 v; } pk;
        if (rr < 3) {
            const float* src = gL + rr * DM + c0;
            float4 f0 = *(const float4*)(src);
            float4 f1 = *(const float4*)(src + 4);
            pk.us[0] = f2bf(f0.x); pk.us[1] = f2bf(f0.y); pk.us[2] = f2bf(f0.z); pk.us[3] = f2bf(f0.w);
            pk.us[4] = f2bf(f1.x); pk.us[5] = f2bf(f1.y); pk.us[6] = f2bf(f1.z); pk.us[7] = f2bf(f1.w);
        } else pk.v = make_uint4(0, 0, 0, 0);
        *(uint4*)(actA + ((rr * 256 + c0 * 2) ^ swz)) = pk.v;
    }
    __syncthreads();

    f32x4 acc[2];
    const int cA = (2 * w) * 16 + l15, cB = (2 * w + 1) * 16 + l15;
    {   // layer 1
        float ba = b1[cA], bb = b1[cB];
        acc[0] = (f32x4){ba, ba, ba, ba};
        acc[1] = (f32x4){bb, bb, bb, bb};
        mmw(actA, l, whi + (size_t)s1 * 16384 + w * 4096, wlo + (size_t)s1 * 16384 + w * 4096, acc);
        __syncthreads();
        store_act(actB, l, w, acc);
        __syncthreads();
    }
    {   // layer 2
        float ba = b2[cA], bb = b2[cB];
        acc[0] = (f32x4){ba, ba, ba, ba};
        acc[1] = (f32x4){bb, bb, bb, bb};
        mmw(actB, l, whi + (size_t)s2 * 16384 + w * 4096, wlo + (size_t)s2 * 16384 + w * 4096, acc);
        __syncthreads();
        store_act(actA, l, w, acc);
        __syncthreads();
    }
    // projection S
    acc[0] = (f32x4){0.f, 0.f, 0.f, 0.f};
    acc[1] = (f32x4){0.f, 0.f, 0.f, 0.f};
    mmw(actA, l, whi + (size_t)sS * 16384 + w * 4096, wlo + (size_t)sS * 16384 + w * 4096, acc);
#pragma unroll
    for (int ntl = 0; ntl < 2; ++ntl)
#pragma unroll
        for (int i = 0; i < 4; ++i) {
            int row = kgrp * 4 + i;
            if (row < 3)
                hsOut[(size_t)(b * LN + r0 + row) * DM + (2 * w + ntl) * 16 + l15] = acc[ntl][i];
        }
    // projection R (+bp)
    {
        float ba = bp[cA], bb = bp[cB];
        acc[0] = (f32x4){ba, ba, ba, ba};
        acc[1] = (f32x4){bb, bb, bb, bb};
        mmw(actA, l, whi + (size_t)(sS + 1) * 16384 + w * 4096, wlo + (size_t)(sS + 1) * 16384 + w * 4096, acc);
    }
#pragma unroll
    for (int ntl = 0; ntl < 2; ++ntl)
#pragma unroll
        for (int i = 0; i < 4; ++i) {
            int row = kgrp * 4 + i;
            if (row < 3)
                hrOut[(size_t)(b * LN + r0 + row) * DM + (2 * w + ntl) * 16 + l15] = acc[ntl][i];
        }
}

// ---------------- final: out[b][e][c] = elu(hs_f[send]+hr_f[recv]) @ fW2 + fb2 (f32 scalar) ----
// grid (BN, LN): b = blockIdx.x -> blk%8 = b%8 (XCD-aligned)
__global__ void final_kernel(const float* __restrict__ hs, const float* __restrict__ hr,
                             const float* __restrict__ fW2, const float* __restrict__ fb2,
                             float* __restrict__ out) {
    __shared__ float w2l[DM * 6];
    __shared__ float hrbuf[DM];
    const int b = blockIdx.x, r = blockIdx.y;
    const int t = threadIdx.x;   // 128 threads
    hrbuf[t] = hr[((size_t)b * LN + r) * DM + t];
    for (int c = 0; c < 6; ++c) w2l[t * 6 + c] = fW2[t * 6 + c];
    __syncthreads();
    int k = t;
    if (k < EPN) {
        int j = k + (k >= r);
        const float* src = hs + ((size_t)b * LN + j) * DM;
        float acc[6];
        for (int c = 0; c < 6; ++c) acc[c] = fb2[c];
        for (int d0 = 0; d0 < DM; d0 += 4) {
            float4 f = *(const float4*)(src + d0);
            float v0 = eluf(f.x + hrbuf[d0 + 0]);
            float v1 = eluf(f.y + hrbuf[d0 + 1]);
            float v2 = eluf(f.z + hrbuf[d0 + 2]);
            float v3 = eluf(f.w + hrbuf[d0 + 3]);
            for (int c = 0; c < 6; ++c)
                acc[c] += v0 * w2l[(d0 + 0) * 6 + c] + v1 * w2l[(d0 + 1) * 6 + c]
                        + v2 * w2l[(d0 + 2) * 6 + c] + v3 * w2l[(d0 + 3) * 6 + c];
        }
        float* o = out + (((size_t)b * (LN * EPN)) + r * EPN + k) * 6;
        for (int c = 0; c < 6; ++c) o[c] = acc[c];
    }
}

extern "C" void kernel_launch(void* const* d_in, const int* in_sizes, int n_in,
                              void* d_out, int out_size, void* d_ws, size_t ws_size,
                              hipStream_t stream) {
    const float* inputs = (const float*)d_in[0];
    const float* W0a = (const float*)d_in[3];
    const float* b0a = (const float*)d_in[4];
    const float* W0b = (const float*)d_in[5];
    const float* b0b = (const float*)d_in[6];
    const float* eW1 = (const float*)d_in[7];
    const float* eb1 = (const float*)d_in[8];
    const float* eW2 = (const float*)d_in[9];
    const float* eb2 = (const float*)d_in[10];
    const float* nW1 = (const float*)d_in[11];
    const float* nb1 = (const float*)d_in[12];
    const float* nW2 = (const float*)d_in[13];
    const float* nb2 = (const float*)d_in[14];
    const float* fW1 = (const float*)d_in[15];
    const float* fb1 = (const float*)d_in[16];
    const float* fW2 = (const float*)d_in[17];
    const float* fb2 = (const float*)d_in[18];
    float* out = (float*)d_out;

    const int NR = BN * LN;                                 // 3072 node rows
    unsigned short* whi = (unsigned short*)d_ws;            // 19 x 16384 bf16 hi
    unsigned short* wlo = whi + 19 * 16384;                 // 19 x 16384 bf16 lo
    float* hsA = (float*)(wlo + 19 * 16384);
    float* hrA = hsA + NR * DM;
    float* hsB = hrA + NR * DM;
    float* hrB = hsB + NR * DM;

    SrcTab tab;
    tab.p[0] = eW2;          tab.p[1] = eW2 + 16384;  tab.p[2] = eW2 + 32768;
    tab.p[3] = W0b;
    tab.p[4] = eW1;          tab.p[5] = eW1 + 16384;
    tab.p[6] = nW1;          tab.p[7] = nW2;          tab.p[8] = eW1 + 32768;  tab.p[9]  = eW1 + 49152;
    tab.p[10] = nW1 + 16384; tab.p[11] = nW2 + 16384; tab.p[12] = eW1 + 65536; tab.p[13] = eW1 + 81920;
    tab.p[14] = nW1 + 32768; tab.p[15] = nW2 + 32768; tab.p[16] = fW1;         tab.p[17] = fW1 + 16384;
    tab.p[18] = fW2;

    #define WM(m) (whi + (m) * 16384), (wlo + (m) * 16384)

    conv_pack_kernel<<<152, 256, 0, stream>>>(tab, whi, wlo);
    node0_kernel<<<192, 256, 0, stream>>>(inputs, W0a, b0a, WM(3), b0b, WM(4), WM(5), eb1, hsA, hrA);
    edge_node_kernel<<<1024, 256, 0, stream>>>(hsA, hrA, whi, wlo, 0, eb2,
                                               6, 7, 8, nb1, nb2, eb1 + DM, hsB, hrB);
    edge_node_kernel<<<1024, 256, 0, stream>>>(hsB, hrB, whi, wlo, 1, eb2 + DM,
                                               10, 11, 12, nb1 + DM, nb2 + DM, eb1 + 2 * DM, hsA, hrA);
    edge_node_kernel<<<1024, 256, 0, stream>>>(hsA, hrA, whi, wlo, 2, eb2 + 2 * DM,
                                               14, 15, 16, nb1 + 2 * DM, nb2 + 2 * DM, fb1, hsB, hrB);
    final_kernel<<<dim3(BN, LN), 128, 0, stream>>>(hsB, hrB, fW2, fb2, out);
    #undef WM
}

// Round 10
// 128.813 us; speedup vs baseline: 2.3244x; 1.0711x over previous
//
#include <hip/hip_runtime.h>
#include <hip/hip_bf16.h>

#define LN 96
#define BN 32
#define DM 128
#define EPN 95   // edges per receiver = L-1

typedef __attribute__((ext_vector_type(8))) short s16x8;
typedef __attribute__((ext_vector_type(4))) float f32x4;

__device__ __forceinline__ float eluf(float x){ return x > 0.f ? x : __expf(x) - 1.f; }
__device__ __forceinline__ unsigned short f2bf(float f){
    unsigned u = __float_as_uint(f);
    return (unsigned short)((u + 0x7fff + ((u >> 16) & 1)) >> 16);
}
__device__ __forceinline__ float bf2f(unsigned short h){ return __uint_as_float(((unsigned)h) << 16); }
// packed RNE f32->bf16 pair (1 instruction): D[15:0]=bf16(lo), D[31:16]=bf16(hi)
__device__ __forceinline__ unsigned cvtpk(float lo, float hi){
    unsigned r;
    asm("v_cvt_pk_bf16_f32 %0, %1, %2" : "=v"(r) : "v"(lo), "v"(hi));
    return r;
}

// ---------------- weight pack: 19 slots, fragment-order bf16 hi+lo ----------------
// chunk c=(nt*4+ks)*64+lane holds 8 elems: n = nt*16+(lane&15), k = ks*32+(lane>>4)*8+e
// slots: 0..2 eW2[i]; 3 W0b; 4,5 eW1[0] S/R; 6 nW1[0]; 7 nW2[0]; 8,9 eW1[1] S/R;
//        10 nW1[1]; 11 nW2[1]; 12,13 eW1[2] S/R; 14 nW1[2]; 15 nW2[2]; 16,17 fW1 S/R;
//        18 fW2 (unused; final stays f32 scalar)
struct SrcTab { const float* p[19]; };

__global__ void conv_pack_kernel(SrcTab tab, unsigned short* __restrict__ hi,
                                 unsigned short* __restrict__ lo){
    int tid = blockIdx.x * 256 + threadIdx.x;   // 19*2048 = 38912
    int m = tid >> 11, c = tid & 2047;
    int l = c & 63, f = c >> 6;
    int n = (f >> 2) * 16 + (l & 15);
    int k0 = (f & 3) * 32 + (l >> 4) * 8;
    union { unsigned short us[8]; uint4 v; } ph, pl;
#pragma unroll
    for (int e = 0; e < 8; ++e){
        float x;
        if (m == 18) x = (n < 6) ? tab.p[18][(k0 + e) * 6 + n] : 0.f;
        else         x = tab.p[m][(k0 + e) * DM + n];
        unsigned short h = f2bf(x);
        ph.us[e] = h;
        pl.us[e] = f2bf(x - bf2f(h));
    }
    *(uint4*)(hi + (size_t)tid * 8) = ph.v;
    *(uint4*)(lo + (size_t)tid * 8) = pl.v;
}

// ---------------- wave-level 16x32 matmul step (2 n-tiles per wave, hi+lo) ----------------
__device__ __forceinline__ void mmw(const char* atile, int l,
                                    const unsigned short* __restrict__ whW,
                                    const unsigned short* __restrict__ wlW,
                                    f32x4 acc[2]) {
    const int l15 = l & 15, kgrp = l >> 4;
    s16x8 a[4];
#pragma unroll
    for (int ks = 0; ks < 4; ++ks)
        a[ks] = *(const s16x8*)(atile + ((l15 * 256 + (ks * 32 + kgrp * 8) * 2) ^ ((l15 & 7) << 4)));
#pragma unroll
    for (int ntl = 0; ntl < 2; ++ntl) {
#pragma unroll
        for (int ks = 0; ks < 4; ++ks) {
            s16x8 bh = *(const s16x8*)(whW + (size_t)((ntl * 4 + ks) * 64 + l) * 8);
            acc[ntl] = __builtin_amdgcn_mfma_f32_16x16x32_bf16(a[ks], bh, acc[ntl], 0, 0, 0);
        }
#pragma unroll
        for (int ks = 0; ks < 4; ++ks) {
            s16x8 bl = *(const s16x8*)(wlW + (size_t)((ntl * 4 + ks) * 64 + l) * 8);
            acc[ntl] = __builtin_amdgcn_mfma_f32_16x16x32_bf16(a[ks], bl, acc[ntl], 0, 0, 0);
        }
    }
}

__device__ __forceinline__ void store_act(char* atile, int l, int w, f32x4 acc[2]) {
    const int l15 = l & 15, kgrp = l >> 4;
#pragma unroll
    for (int ntl = 0; ntl < 2; ++ntl)
#pragma unroll
        for (int i = 0; i < 4; ++i) {
            int row = kgrp * 4 + i;              // C/D: col=lane&15, row=(lane>>4)*4+i
            int col = (2 * w + ntl) * 16 + l15;
            *(unsigned short*)(atile + ((row * 256 + col * 2) ^ ((row & 7) << 4))) = f2bf(eluf(acc[ntl][i]));
        }
}

// ---------------- node0: input MLP (scalar W0a, MFMA W0b) + proj eW1[0] ----------------
// 192 blocks x 256 thr; 16 rows/block; XCD-aligned: blk = q*32 + b (batch in low 5 bits)
__global__ __launch_bounds__(256) void node0_kernel(
    const float* __restrict__ in,
    const float* __restrict__ W0a, const float* __restrict__ b0a,
    const unsigned short* __restrict__ w2h, const unsigned short* __restrict__ w2l,
    const float* __restrict__ b2,
    const unsigned short* __restrict__ wsh, const unsigned short* __restrict__ wsl,
    const unsigned short* __restrict__ wrh, const unsigned short* __restrict__ wrl,
    const float* __restrict__ bp,
    float* __restrict__ hs, float* __restrict__ hr) {
    __shared__ char atile[16 * 256];
    const int t = threadIdx.x;
    const int q = blockIdx.x >> 5, bblk = blockIdx.x & 31;
    const int row0 = bblk * LN + q * 16;
    const int l = t & 63, w = t >> 6;
    const int l15 = l & 15, kgrp = l >> 4;

    {   // fused scalar K=4 layer (W0a) -> bf16 tile
        int rr = t >> 4, qq = t & 15, c0 = qq * 8;
        int swz = (rr & 7) << 4;
        union { unsigned short us[8]; uint4 v; } pk;
        int row = row0 + rr;
        int b = row / LN, ll = row - b * LN;
        float4 x = *(const float4*)(in + (size_t)(ll * BN + b) * 4);
#pragma unroll
        for (int j = 0; j < 8; ++j) {
            int cc = c0 + j;
            float a = b0a[cc] + x.x * W0a[cc] + x.y * W0a[DM + cc]
                    + x.z * W0a[2 * DM + cc] + x.w * W0a[3 * DM + cc];
            pk.us[j] = f2bf(eluf(a));
        }
        *(uint4*)(atile + ((rr * 256 + c0 * 2) ^ swz)) = pk.v;
    }
    __syncthreads();

    f32x4 acc[2];
    const int cA = (2 * w) * 16 + l15, cB = (2 * w + 1) * 16 + l15;
    {   // layer W0b
        float ba = b2[cA], bb = b2[cB];
        acc[0] = (f32x4){ba, ba, ba, ba};
        acc[1] = (f32x4){bb, bb, bb, bb};
        mmw(atile, l, w2h + w * 4096, w2l + w * 4096, acc);
        __syncthreads();
        store_act(atile, l, w, acc);
        __syncthreads();
    }
    // projection S
    acc[0] = (f32x4){0.f, 0.f, 0.f, 0.f};
    acc[1] = (f32x4){0.f, 0.f, 0.f, 0.f};
    mmw(atile, l, wsh + w * 4096, wsl + w * 4096, acc);
#pragma unroll
    for (int ntl = 0; ntl < 2; ++ntl)
#pragma unroll
        for (int i = 0; i < 4; ++i)
            hs[(size_t)(row0 + kgrp * 4 + i) * DM + (2 * w + ntl) * 16 + l15] = acc[ntl][i];
    // projection R (+bp)
    {
        float ba = bp[cA], bb = bp[cB];
        acc[0] = (f32x4){ba, ba, ba, ba};
        acc[1] = (f32x4){bb, bb, bb, bb};
        mmw(atile, l, wrh + w * 4096, wrl + w * 4096, acc);
    }
#pragma unroll
    for (int ntl = 0; ntl < 2; ++ntl)
#pragma unroll
        for (int i = 0; i < 4; ++i)
            hr[(size_t)(row0 + kgrp * 4 + i) * DM + (2 * w + ntl) * 16 + l15] = acc[ntl][i];
}

// ---------------- fused edge+node: 512 blocks x 256 thr; block owns 6 receivers ----------------
// XCD-aligned: blk = rg*32 + b -> blk%8 = b%8 (batch's producers and consumers share one XCD L2)
// 6 receivers/block halves per-launch weight re-fetch vs 3/block (node tail: 6 rows per
// 128x128x4-matrix read instead of 3; edge B-frags: 512 instead of 1024 copies).
__global__ __launch_bounds__(256) void edge_node_kernel(
    const float* __restrict__ hsIn, const float* __restrict__ hrIn,
    const unsigned short* __restrict__ whi, const unsigned short* __restrict__ wlo,
    int eslot, const float* __restrict__ eb2v,
    int s1, int s2, int sS,
    const float* __restrict__ b1, const float* __restrict__ b2, const float* __restrict__ bp,
    float* __restrict__ hsOut, float* __restrict__ hrOut) {
    __shared__ char y1[LN * 256];     // 96x128 bf16, XOR-swizzled
    __shared__ float hrL[6 * DM];
    __shared__ float gL[6 * DM];
    __shared__ char actA[16 * 256];
    __shared__ char actB[16 * 256];
    const int blk = blockIdx.x;
    const int rg = blk >> 5, b = blk & 31;   // rg 0..15, r0 = rg*6
    const int r0 = rg * 6;
    const int t = threadIdx.x;
    const int w = t >> 6, l = t & 63;
    const int l15 = l & 15, kgrp = l >> 4;

    if (t < 192) {
        int rr = t >> 5, c4 = (t & 31) * 4;
        *(float4*)(hrL + rr * DM + c4) = *(const float4*)(hrIn + ((size_t)(b * LN + r0 + rr)) * DM + c4);
    }
    // edge B-frags (hi only), wave n-split
    s16x8 bfr[2][4];
#pragma unroll
    for (int ntl = 0; ntl < 2; ++ntl)
#pragma unroll
        for (int ks = 0; ks < 4; ++ks)
            bfr[ntl][ks] = *(const s16x8*)(whi + (size_t)eslot * 16384 +
                           (size_t)(((2 * w + ntl) * 4 + ks) * 64 + l) * 8);
    float b20 = eb2v[(2 * w) * 16 + l15], b21 = eb2v[(2 * w + 1) * 16 + l15];
    __syncthreads();

    const float* hsB = hsIn + (size_t)(b * LN) * DM;
    for (int rr6 = 0; rr6 < 6; ++rr6) {
        int r = r0 + rr6;
        // build y1: 1536 tasks; 3 chunks of 2 reps with hoisted global loads
#pragma unroll
        for (int ch = 0; ch < 3; ++ch) {
            float4 h0[2], h1[2];
            int rrs[2], c0s[2];
#pragma unroll
            for (int k = 0; k < 2; ++k) {
                int task = t + (ch * 2 + k) * 256;
                int rr = task >> 4, c0 = (task & 15) * 8;
                rrs[k] = rr; c0s[k] = c0;
                if (rr < EPN) {
                    int j = rr + (rr >= r);
                    const float* hp = hsB + (size_t)j * DM + c0;
                    h0[k] = *(const float4*)hp;
                    h1[k] = *(const float4*)(hp + 4);
                }
            }
#pragma unroll
            for (int k = 0; k < 2; ++k) {
                int rr = rrs[k], c0 = c0s[k];
                int swz = (rr & 7) << 4;
                uint4 pk = make_uint4(0, 0, 0, 0);
                if (rr < EPN) {
                    const float* rp = hrL + rr6 * DM + c0;
                    f32x4 v0 = *(const f32x4*)rp, v1 = *(const f32x4*)(rp + 4);
                    float e0 = eluf(h0[k].x + v0[0]), e1 = eluf(h0[k].y + v0[1]);
                    float e2 = eluf(h0[k].z + v0[2]), e3 = eluf(h0[k].w + v0[3]);
                    float e4 = eluf(h1[k].x + v1[0]), e5 = eluf(h1[k].y + v1[1]);
                    float e6 = eluf(h1[k].z + v1[2]), e7 = eluf(h1[k].w + v1[3]);
                    pk.x = cvtpk(e0, e1); pk.y = cvtpk(e2, e3);
                    pk.z = cvtpk(e4, e5); pk.w = cvtpk(e6, e7);
                }
                *(uint4*)(y1 + ((rr * 256 + c0 * 2) ^ swz)) = pk;
            }
        }
        __syncthreads();
        // MFMA + epilogue (n-split: wave owns 32 cols)
        f32x4 acc[6][2] = {};
#pragma unroll
        for (int mt = 0; mt < 6; ++mt) {
            int arow = mt * 16 + l15;
            const char* rb = y1 + arow * 256;
            int swz = (arow & 7) << 4;
#pragma unroll
            for (int ks = 0; ks < 4; ++ks) {
                s16x8 a = *(const s16x8*)(rb + (((ks * 32 + kgrp * 8) * 2) ^ swz));
                acc[mt][0] = __builtin_amdgcn_mfma_f32_16x16x32_bf16(a, bfr[0][ks], acc[mt][0], 0, 0, 0);
                acc[mt][1] = __builtin_amdgcn_mfma_f32_16x16x32_bf16(a, bfr[1][ks], acc[mt][1], 0, 0, 0);
            }
        }
        float cs0 = 0.f, cs1 = 0.f;
#pragma unroll
        for (int mt = 0; mt < 6; ++mt)
#pragma unroll
            for (int i = 0; i < 4; ++i) {
                int row = mt * 16 + kgrp * 4 + i;
                if (row < EPN) {
                    cs0 += eluf(acc[mt][0][i] + b20);
                    cs1 += eluf(acc[mt][1][i] + b21);
                }
            }
        cs0 += __shfl_xor(cs0, 16); cs0 += __shfl_xor(cs0, 32);
        cs1 += __shfl_xor(cs1, 16); cs1 += __shfl_xor(cs1, 32);
        if (l < 16) {
            gL[rr6 * DM + (2 * w) * 16 + l]     = cs0 * (1.f / 95.f);
            gL[rr6 * DM + (2 * w + 1) * 16 + l] = cs1 * (1.f / 95.f);
        }
        __syncthreads();
    }

    // ---------- node tail on the 6 g rows ----------
    {
        int rr = t >> 4, q = t & 15, c0 = q * 8;
        int swz = (rr & 7) << 4;
        union { unsigned short us[8]; uint4 v; } pk;
        if (rr < 6) {
            const float* src = gL + rr * DM + c0;
            float4 f0 = *(const float4*)(src);
            float4 f1 = *(const float4*)(src + 4);
            pk.us[0] = f2bf(f0.x); pk.us[1] = f2bf(f0.y); pk.us[2] = f2bf(f0.z); pk.us[3] = f2bf(f0.w);
            pk.us[4] = f2bf(f1.x); pk.us[5] = f2bf(f1.y); pk.us[6] = f2bf(f1.z); pk.us[7] = f2bf(f1.w);
        } else pk.v = make_uint4(0, 0, 0, 0);
        *(uint4*)(actA + ((rr * 256 + c0 * 2) ^ swz)) = pk.v;
    }
    __syncthreads();

    f32x4 acc[2];
    const int cA = (2 * w) * 16 + l15, cB = (2 * w + 1) * 16 + l15;
    {   // layer 1
        float ba = b1[cA], bb = b1[cB];
        acc[0] = (f32x4){ba, ba, ba, ba};
        acc[1] = (f32x4){bb, bb, bb, bb};
        mmw(actA, l, whi + (size_t)s1 * 16384 + w * 4096, wlo + (size_t)s1 * 16384 + w * 4096, acc);
        __syncthreads();
        store_act(actB, l, w, acc);
        __syncthreads();
    }
    {   // layer 2
        float ba = b2[cA], bb = b2[cB];
        acc[0] = (f32x4){ba, ba, ba, ba};
        acc[1] = (f32x4){bb, bb, bb, bb};
        mmw(actB, l, whi + (size_t)s2 * 16384 + w * 4096, wlo + (size_t)s2 * 16384 + w * 4096, acc);
        __syncthreads();
        store_act(actA, l, w, acc);
        __syncthreads();
    }
    // projection S
    acc[0] = (f32x4){0.f, 0.f, 0.f, 0.f};
    acc[1] = (f32x4){0.f, 0.f, 0.f, 0.f};
    mmw(actA, l, whi + (size_t)sS * 16384 + w * 4096, wlo + (size_t)sS * 16384 + w * 4096, acc);
#pragma unroll
    for (int ntl = 0; ntl < 2; ++ntl)
#pragma unroll
        for (int i = 0; i < 4; ++i) {
            int row = kgrp * 4 + i;
            if (row < 6)
                hsOut[(size_t)(b * LN + r0 + row) * DM + (2 * w + ntl) * 16 + l15] = acc[ntl][i];
        }
    // projection R (+bp)
    {
        float ba = bp[cA], bb = bp[cB];
        acc[0] = (f32x4){ba, ba, ba, ba};
        acc[1] = (f32x4){bb, bb, bb, bb};
        mmw(actA, l, whi + (size_t)(sS + 1) * 16384 + w * 4096, wlo + (size_t)(sS + 1) * 16384 + w * 4096, acc);
    }
#pragma unroll
    for (int ntl = 0; ntl < 2; ++ntl)
#pragma unroll
        for (int i = 0; i < 4; ++i) {
            int row = kgrp * 4 + i;
            if (row < 6)
                hrOut[(size_t)(b * LN + r0 + row) * DM + (2 * w + ntl) * 16 + l15] = acc[ntl][i];
        }
}

// ---------------- final: out[b][e][c] = elu(hs_f[send]+hr_f[recv]) @ fW2 + fb2 (f32 scalar) ----
// grid (BN, LN): b = blockIdx.x -> blk%8 = b%8 (XCD-aligned)
__global__ void final_kernel(const float* __restrict__ hs, const float* __restrict__ hr,
                             const float* __restrict__ fW2, const float* __restrict__ fb2,
                             float* __restrict__ out) {
    __shared__ float w2l[DM * 6];
    __shared__ float hrbuf[DM];
    const int b = blockIdx.x, r = blockIdx.y;
    const int t = threadIdx.x;   // 128 threads
    hrbuf[t] = hr[((size_t)b * LN + r) * DM + t];
    for (int c = 0; c < 6; ++c) w2l[t * 6 + c] = fW2[t * 6 + c];
    __syncthreads();
    int k = t;
    if (k < EPN) {
        int j = k + (k >= r);
        const float* src = hs + ((size_t)b * LN + j) * DM;
        float acc[6];
        for (int c = 0; c < 6; ++c) acc[c] = fb2[c];
        for (int d0 = 0; d0 < DM; d0 += 4) {
            float4 f = *(const float4*)(src + d0);
            float v0 = eluf(f.x + hrbuf[d0 + 0]);
            float v1 = eluf(f.y + hrbuf[d0 + 1]);
            float v2 = eluf(f.z + hrbuf[d0 + 2]);
            float v3 = eluf(f.w + hrbuf[d0 + 3]);
            for (int c = 0; c < 6; ++c)
                acc[c] += v0 * w2l[(d0 + 0) * 6 + c] + v1 * w2l[(d0 + 1) * 6 + c]
                        + v2 * w2l[(d0 + 2) * 6 + c] + v3 * w2l[(d0 + 3) * 6 + c];
        }
        float* o = out + (((size_t)b * (LN * EPN)) + r * EPN + k) * 6;
        for (int c = 0; c < 6; ++c) o[c] = acc[c];
    }
}

extern "C" void kernel_launch(void* const* d_in, const int* in_sizes, int n_in,
                              void* d_out, int out_size, void* d_ws, size_t ws_size,
                              hipStream_t stream) {
    const float* inputs = (const float*)d_in[0];
    const float* W0a = (const float*)d_in[3];
    const float* b0a = (const float*)d_in[4];
    const float* W0b = (const float*)d_in[5];
    const float* b0b = (const float*)d_in[6];
    const float* eW1 = (const float*)d_in[7];
    const float* eb1 = (const float*)d_in[8];
    const float* eW2 = (const float*)d_in[9];
    const float* eb2 = (const float*)d_in[10];
    const float* nW1 = (const float*)d_in[11];
    const float* nb1 = (const float*)d_in[12];
    const float* nW2 = (const float*)d_in[13];
    const float* nb2 = (const float*)d_in[14];
    const float* fW1 = (const float*)d_in[15];
    const float* fb1 = (const float*)d_in[16];
    const float* fW2 = (const float*)d_in[17];
    const float* fb2 = (const float*)d_in[18];
    float* out = (float*)d_out;

    const int NR = BN * LN;                                 // 3072 node rows
    unsigned short* whi = (unsigned short*)d_ws;            // 19 x 16384 bf16 hi
    unsigned short* wlo = whi + 19 * 16384;                 // 19 x 16384 bf16 lo
    float* hsA = (float*)(wlo + 19 * 16384);
    float* hrA = hsA + NR * DM;
    float* hsB = hrA + NR * DM;
    float* hrB = hsB + NR * DM;

    SrcTab tab;
    tab.p[0] = eW2;          tab.p[1] = eW2 + 16384;  tab.p[2] = eW2 + 32768;
    tab.p[3] = W0b;
    tab.p[4] = eW1;          tab.p[5] = eW1 + 16384;
    tab.p[6] = nW1;          tab.p[7] = nW2;          tab.p[8] = eW1 + 32768;  tab.p[9]  = eW1 + 49152;
    tab.p[10] = nW1 + 16384; tab.p[11] = nW2 + 16384; tab.p[12] = eW1 + 65536; tab.p[13] = eW1 + 81920;
    tab.p[14] = nW1 + 32768; tab.p[15] = nW2 + 32768; tab.p[16] = fW1;         tab.p[17] = fW1 + 16384;
    tab.p[18] = fW2;

    #define WM(m) (whi + (m) * 16384), (wlo + (m) * 16384)

    conv_pack_kernel<<<152, 256, 0, stream>>>(tab, whi, wlo);
    node0_kernel<<<192, 256, 0, stream>>>(inputs, W0a, b0a, WM(3), b0b, WM(4), WM(5), eb1, hsA, hrA);
    edge_node_kernel<<<512, 256, 0, stream>>>(hsA, hrA, whi, wlo, 0, eb2,
                                              6, 7, 8, nb1, nb2, eb1 + DM, hsB, hrB);
    edge_node_kernel<<<512, 256, 0, stream>>>(hsB, hrB, whi, wlo, 1, eb2 + DM,
                                              10, 11, 12, nb1 + DM, nb2 + DM, eb1 + 2 * DM, hsA, hrA);
    edge_node_kernel<<<512, 256, 0, stream>>>(hsA, hrA, whi, wlo, 2, eb2 + 2 * DM,
                                              14, 15, 16, nb1 + 2 * DM, nb2 + 2 * DM, fb1, hsB, hrB);
    final_kernel<<<dim3(BN, LN), 128, 0, stream>>>(hsB, hrB, fW2, fb2, out);
    #undef WM
}

// Round 11
// 125.131 us; speedup vs baseline: 2.3928x; 1.0294x over previous
//
#include <hip/hip_runtime.h>
#include <hip/hip_bf16.h>

#define LN 96
#define BN 32
#define DM 128
#define EPN 95   // edges per receiver = L-1

typedef __attribute__((ext_vector_type(8))) short s16x8;
typedef __attribute__((ext_vector_type(4))) float f32x4;

__device__ __forceinline__ float eluf(float x){ return x > 0.f ? x : __expf(x) - 1.f; }
__device__ __forceinline__ unsigned short f2bf(float f){
    unsigned u = __float_as_uint(f);
    return (unsigned short)((u + 0x7fff + ((u >> 16) & 1)) >> 16);
}
__device__ __forceinline__ float bf2f(unsigned short h){ return __uint_as_float(((unsigned)h) << 16); }
// packed RNE f32->bf16 pair (1 instruction): D[15:0]=bf16(lo), D[31:16]=bf16(hi)
__device__ __forceinline__ unsigned cvtpk(float lo, float hi){
    unsigned r;
    asm("v_cvt_pk_bf16_f32 %0, %1, %2" : "=v"(r) : "v"(lo), "v"(hi));
    return r;
}

// ---------------- weight pack: 19 slots, fragment-order bf16 hi+lo ----------------
// chunk c=(nt*4+ks)*64+lane holds 8 elems: n = nt*16+(lane&15), k = ks*32+(lane>>4)*8+e
// slots: 0..2 eW2[i]; 3 W0b; 4,5 eW1[0] S/R; 6 nW1[0]; 7 nW2[0]; 8,9 eW1[1] S/R;
//        10 nW1[1]; 11 nW2[1]; 12,13 eW1[2] S/R; 14 nW1[2]; 15 nW2[2]; 16,17 fW1 S/R;
//        18 fW2 (128x6 zero-padded to 128x16)
struct SrcTab { const float* p[19]; };

__global__ void conv_pack_kernel(SrcTab tab, unsigned short* __restrict__ hi,
                                 unsigned short* __restrict__ lo){
    int tid = blockIdx.x * 256 + threadIdx.x;   // 19*2048 = 38912
    int m = tid >> 11, c = tid & 2047;
    int l = c & 63, f = c >> 6;
    int n = (f >> 2) * 16 + (l & 15);
    int k0 = (f & 3) * 32 + (l >> 4) * 8;
    union { unsigned short us[8]; uint4 v; } ph, pl;
#pragma unroll
    for (int e = 0; e < 8; ++e){
        float x;
        if (m == 18) x = (n < 6) ? tab.p[18][(k0 + e) * 6 + n] : 0.f;
        else         x = tab.p[m][(k0 + e) * DM + n];
        unsigned short h = f2bf(x);
        ph.us[e] = h;
        pl.us[e] = f2bf(x - bf2f(h));
    }
    *(uint4*)(hi + (size_t)tid * 8) = ph.v;
    *(uint4*)(lo + (size_t)tid * 8) = pl.v;
}

// ---------------- wave-level 16x32 matmul step (2 n-tiles per wave, hi+lo) ----------------
__device__ __forceinline__ void mmw(const char* atile, int l,
                                    const unsigned short* __restrict__ whW,
                                    const unsigned short* __restrict__ wlW,
                                    f32x4 acc[2]) {
    const int l15 = l & 15, kgrp = l >> 4;
    s16x8 a[4];
#pragma unroll
    for (int ks = 0; ks < 4; ++ks)
        a[ks] = *(const s16x8*)(atile + ((l15 * 256 + (ks * 32 + kgrp * 8) * 2) ^ ((l15 & 7) << 4)));
#pragma unroll
    for (int ntl = 0; ntl < 2; ++ntl) {
#pragma unroll
        for (int ks = 0; ks < 4; ++ks) {
            s16x8 bh = *(const s16x8*)(whW + (size_t)((ntl * 4 + ks) * 64 + l) * 8);
            acc[ntl] = __builtin_amdgcn_mfma_f32_16x16x32_bf16(a[ks], bh, acc[ntl], 0, 0, 0);
        }
#pragma unroll
        for (int ks = 0; ks < 4; ++ks) {
            s16x8 bl = *(const s16x8*)(wlW + (size_t)((ntl * 4 + ks) * 64 + l) * 8);
            acc[ntl] = __builtin_amdgcn_mfma_f32_16x16x32_bf16(a[ks], bl, acc[ntl], 0, 0, 0);
        }
    }
}

__device__ __forceinline__ void store_act(char* atile, int l, int w, f32x4 acc[2]) {
    const int l15 = l & 15, kgrp = l >> 4;
#pragma unroll
    for (int ntl = 0; ntl < 2; ++ntl)
#pragma unroll
        for (int i = 0; i < 4; ++i) {
            int row = kgrp * 4 + i;              // C/D: col=lane&15, row=(lane>>4)*4+i
            int col = (2 * w + ntl) * 16 + l15;
            *(unsigned short*)(atile + ((row * 256 + col * 2) ^ ((row & 7) << 4))) = f2bf(eluf(acc[ntl][i]));
        }
}

// ---------------- node0: input MLP (scalar W0a, MFMA W0b) + proj eW1[0] ----------------
// 192 blocks x 256 thr; 16 rows/block; XCD-aligned: blk = q*32 + b (batch in low 5 bits)
__global__ __launch_bounds__(256) void node0_kernel(
    const float* __restrict__ in,
    const float* __restrict__ W0a, const float* __restrict__ b0a,
    const unsigned short* __restrict__ w2h, const unsigned short* __restrict__ w2l,
    const float* __restrict__ b2,
    const unsigned short* __restrict__ wsh, const unsigned short* __restrict__ wsl,
    const unsigned short* __restrict__ wrh, const unsigned short* __restrict__ wrl,
    const float* __restrict__ bp,
    float* __restrict__ hs, float* __restrict__ hr) {
    __shared__ char atile[16 * 256];
    const int t = threadIdx.x;
    const int q = blockIdx.x >> 5, bblk = blockIdx.x & 31;
    const int row0 = bblk * LN + q * 16;
    const int l = t & 63, w = t >> 6;
    const int l15 = l & 15, kgrp = l >> 4;

    {   // fused scalar K=4 layer (W0a) -> bf16 tile
        int rr = t >> 4, qq = t & 15, c0 = qq * 8;
        int swz = (rr & 7) << 4;
        union { unsigned short us[8]; uint4 v; } pk;
        int row = row0 + rr;
        int b = row / LN, ll = row - b * LN;
        float4 x = *(const float4*)(in + (size_t)(ll * BN + b) * 4);
#pragma unroll
        for (int j = 0; j < 8; ++j) {
            int cc = c0 + j;
            float a = b0a[cc] + x.x * W0a[cc] + x.y * W0a[DM + cc]
                    + x.z * W0a[2 * DM + cc] + x.w * W0a[3 * DM + cc];
            pk.us[j] = f2bf(eluf(a));
        }
        *(uint4*)(atile + ((rr * 256 + c0 * 2) ^ swz)) = pk.v;
    }
    __syncthreads();

    f32x4 acc[2];
    const int cA = (2 * w) * 16 + l15, cB = (2 * w + 1) * 16 + l15;
    {   // layer W0b
        float ba = b2[cA], bb = b2[cB];
        acc[0] = (f32x4){ba, ba, ba, ba};
        acc[1] = (f32x4){bb, bb, bb, bb};
        mmw(atile, l, w2h + w * 4096, w2l + w * 4096, acc);
        __syncthreads();
        store_act(atile, l, w, acc);
        __syncthreads();
    }
    // projection S
    acc[0] = (f32x4){0.f, 0.f, 0.f, 0.f};
    acc[1] = (f32x4){0.f, 0.f, 0.f, 0.f};
    mmw(atile, l, wsh + w * 4096, wsl + w * 4096, acc);
#pragma unroll
    for (int ntl = 0; ntl < 2; ++ntl)
#pragma unroll
        for (int i = 0; i < 4; ++i)
            hs[(size_t)(row0 + kgrp * 4 + i) * DM + (2 * w + ntl) * 16 + l15] = acc[ntl][i];
    // projection R (+bp)
    {
        float ba = bp[cA], bb = bp[cB];
        acc[0] = (f32x4){ba, ba, ba, ba};
        acc[1] = (f32x4){bb, bb, bb, bb};
        mmw(atile, l, wrh + w * 4096, wrl + w * 4096, acc);
    }
#pragma unroll
    for (int ntl = 0; ntl < 2; ++ntl)
#pragma unroll
        for (int i = 0; i < 4; ++i)
            hr[(size_t)(row0 + kgrp * 4 + i) * DM + (2 * w + ntl) * 16 + l15] = acc[ntl][i];
}

// ---------------- fused edge+node: 512 blocks x 256 thr; block owns 6 receivers ----------------
// XCD-aligned: blk = rg*32 + b -> blk%8 = b%8 (batch's producers and consumers share one XCD L2)
__global__ __launch_bounds__(256) void edge_node_kernel(
    const float* __restrict__ hsIn, const float* __restrict__ hrIn,
    const unsigned short* __restrict__ whi, const unsigned short* __restrict__ wlo,
    int eslot, const float* __restrict__ eb2v,
    int s1, int s2, int sS,
    const float* __restrict__ b1, const float* __restrict__ b2, const float* __restrict__ bp,
    float* __restrict__ hsOut, float* __restrict__ hrOut) {
    __shared__ char y1[LN * 256];     // 96x128 bf16, XOR-swizzled
    __shared__ float hrL[6 * DM];
    __shared__ float gL[6 * DM];
    __shared__ char actA[16 * 256];
    __shared__ char actB[16 * 256];
    const int blk = blockIdx.x;
    const int rg = blk >> 5, b = blk & 31;   // rg 0..15, r0 = rg*6
    const int r0 = rg * 6;
    const int t = threadIdx.x;
    const int w = t >> 6, l = t & 63;
    const int l15 = l & 15, kgrp = l >> 4;

    if (t < 192) {
        int rr = t >> 5, c4 = (t & 31) * 4;
        *(float4*)(hrL + rr * DM + c4) = *(const float4*)(hrIn + ((size_t)(b * LN + r0 + rr)) * DM + c4);
    }
    // edge B-frags (hi only), wave n-split
    s16x8 bfr[2][4];
#pragma unroll
    for (int ntl = 0; ntl < 2; ++ntl)
#pragma unroll
        for (int ks = 0; ks < 4; ++ks)
            bfr[ntl][ks] = *(const s16x8*)(whi + (size_t)eslot * 16384 +
                           (size_t)(((2 * w + ntl) * 4 + ks) * 64 + l) * 8);
    float b20 = eb2v[(2 * w) * 16 + l15], b21 = eb2v[(2 * w + 1) * 16 + l15];
    __syncthreads();

    const float* hsB = hsIn + (size_t)(b * LN) * DM;
    for (int rr6 = 0; rr6 < 6; ++rr6) {
        int r = r0 + rr6;
        // build y1: 1536 tasks; 3 chunks of 2 reps with hoisted global loads
#pragma unroll
        for (int ch = 0; ch < 3; ++ch) {
            float4 h0[2], h1[2];
            int rrs[2], c0s[2];
#pragma unroll
            for (int k = 0; k < 2; ++k) {
                int task = t + (ch * 2 + k) * 256;
                int rr = task >> 4, c0 = (task & 15) * 8;
                rrs[k] = rr; c0s[k] = c0;
                if (rr < EPN) {
                    int j = rr + (rr >= r);
                    const float* hp = hsB + (size_t)j * DM + c0;
                    h0[k] = *(const float4*)hp;
                    h1[k] = *(const float4*)(hp + 4);
                }
            }
#pragma unroll
            for (int k = 0; k < 2; ++k) {
                int rr = rrs[k], c0 = c0s[k];
                int swz = (rr & 7) << 4;
                uint4 pk = make_uint4(0, 0, 0, 0);
                if (rr < EPN) {
                    const float* rp = hrL + rr6 * DM + c0;
                    f32x4 v0 = *(const f32x4*)rp, v1 = *(const f32x4*)(rp + 4);
                    float e0 = eluf(h0[k].x + v0[0]), e1 = eluf(h0[k].y + v0[1]);
                    float e2 = eluf(h0[k].z + v0[2]), e3 = eluf(h0[k].w + v0[3]);
                    float e4 = eluf(h1[k].x + v1[0]), e5 = eluf(h1[k].y + v1[1]);
                    float e6 = eluf(h1[k].z + v1[2]), e7 = eluf(h1[k].w + v1[3]);
                    pk.x = cvtpk(e0, e1); pk.y = cvtpk(e2, e3);
                    pk.z = cvtpk(e4, e5); pk.w = cvtpk(e6, e7);
                }
                *(uint4*)(y1 + ((rr * 256 + c0 * 2) ^ swz)) = pk;
            }
        }
        __syncthreads();
        // MFMA + epilogue (n-split: wave owns 32 cols)
        f32x4 acc[6][2] = {};
#pragma unroll
        for (int mt = 0; mt < 6; ++mt) {
            int arow = mt * 16 + l15;
            const char* rb = y1 + arow * 256;
            int swz = (arow & 7) << 4;
#pragma unroll
            for (int ks = 0; ks < 4; ++ks) {
                s16x8 a = *(const s16x8*)(rb + (((ks * 32 + kgrp * 8) * 2) ^ swz));
                acc[mt][0] = __builtin_amdgcn_mfma_f32_16x16x32_bf16(a, bfr[0][ks], acc[mt][0], 0, 0, 0);
                acc[mt][1] = __builtin_amdgcn_mfma_f32_16x16x32_bf16(a, bfr[1][ks], acc[mt][1], 0, 0, 0);
            }
        }
        float cs0 = 0.f, cs1 = 0.f;
#pragma unroll
        for (int mt = 0; mt < 6; ++mt)
#pragma unroll
            for (int i = 0; i < 4; ++i) {
                int row = mt * 16 + kgrp * 4 + i;
                if (row < EPN) {
                    cs0 += eluf(acc[mt][0][i] + b20);
                    cs1 += eluf(acc[mt][1][i] + b21);
                }
            }
        cs0 += __shfl_xor(cs0, 16); cs0 += __shfl_xor(cs0, 32);
        cs1 += __shfl_xor(cs1, 16); cs1 += __shfl_xor(cs1, 32);
        if (l < 16) {
            gL[rr6 * DM + (2 * w) * 16 + l]     = cs0 * (1.f / 95.f);
            gL[rr6 * DM + (2 * w + 1) * 16 + l] = cs1 * (1.f / 95.f);
        }
        __syncthreads();
    }

    // ---------- node tail on the 6 g rows ----------
    {
        int rr = t >> 4, q = t & 15, c0 = q * 8;
        int swz = (rr & 7) << 4;
        union { unsigned short us[8]; uint4 v; } pk;
        if (rr < 6) {
            const float* src = gL + rr * DM + c0;
            float4 f0 = *(const float4*)(src);
            float4 f1 = *(const float4*)(src + 4);
            pk.us[0] = f2bf(f0.x); pk.us[1] = f2bf(f0.y); pk.us[2] = f2bf(f0.z); pk.us[3] = f2bf(f0.w);
            pk.us[4] = f2bf(f1.x); pk.us[5] = f2bf(f1.y); pk.us[6] = f2bf(f1.z); pk.us[7] = f2bf(f1.w);
        } else pk.v = make_uint4(0, 0, 0, 0);
        *(uint4*)(actA + ((rr * 256 + c0 * 2) ^ swz)) = pk.v;
    }
    __syncthreads();

    f32x4 acc[2];
    const int cA = (2 * w) * 16 + l15, cB = (2 * w + 1) * 16 + l15;
    {   // layer 1
        float ba = b1[cA], bb = b1[cB];
        acc[0] = (f32x4){ba, ba, ba, ba};
        acc[1] = (f32x4){bb, bb, bb, bb};
        mmw(actA, l, whi + (size_t)s1 * 16384 + w * 4096, wlo + (size_t)s1 * 16384 + w * 4096, acc);
        __syncthreads();
        store_act(actB, l, w, acc);
        __syncthreads();
    }
    {   // layer 2
        float ba = b2[cA], bb = b2[cB];
        acc[0] = (f32x4){ba, ba, ba, ba};
        acc[1] = (f32x4){bb, bb, bb, bb};
        mmw(actB, l, whi + (size_t)s2 * 16384 + w * 4096, wlo + (size_t)s2 * 16384 + w * 4096, acc);
        __syncthreads();
        store_act(actA, l, w, acc);
        __syncthreads();
    }
    // projection S
    acc[0] = (f32x4){0.f, 0.f, 0.f, 0.f};
    acc[1] = (f32x4){0.f, 0.f, 0.f, 0.f};
    mmw(actA, l, whi + (size_t)sS * 16384 + w * 4096, wlo + (size_t)sS * 16384 + w * 4096, acc);
#pragma unroll
    for (int ntl = 0; ntl < 2; ++ntl)
#pragma unroll
        for (int i = 0; i < 4; ++i) {
            int row = kgrp * 4 + i;
            if (row < 6)
                hsOut[(size_t)(b * LN + r0 + row) * DM + (2 * w + ntl) * 16 + l15] = acc[ntl][i];
        }
    // projection R (+bp)
    {
        float ba = bp[cA], bb = bp[cB];
        acc[0] = (f32x4){ba, ba, ba, ba};
        acc[1] = (f32x4){bb, bb, bb, bb};
        mmw(actA, l, whi + (size_t)(sS + 1) * 16384 + w * 4096, wlo + (size_t)(sS + 1) * 16384 + w * 4096, acc);
    }
#pragma unroll
    for (int ntl = 0; ntl < 2; ++ntl)
#pragma unroll
        for (int i = 0; i < 4; ++i) {
            int row = kgrp * 4 + i;
            if (row < 6)
                hrOut[(size_t)(b * LN + r0 + row) * DM + (2 * w + ntl) * 16 + l15] = acc[ntl][i];
        }
}

// ---------------- final (MFMA): 512 blocks x 256 thr; block owns 6 receivers (3 pairs) --------
// out[b][r*EPN+k][c] = y1[k] @ fW2 + fb2, y1 = elu(hs_f[send]+hr_f[recv]); fW2 padded to N=16,
// hi+lo split (R4-validated math). XCD-aligned like edge_node.
__global__ __launch_bounds__(256) void final_kernel(
    const float* __restrict__ hs, const float* __restrict__ hr,
    const unsigned short* __restrict__ wfh, const unsigned short* __restrict__ wfl,
    const float* __restrict__ fb2, float* __restrict__ out) {
    __shared__ char tA[LN * 256];
    __shared__ char tB[LN * 256];
    __shared__ float hrL[6 * DM];
    const int blk = blockIdx.x;
    const int rg = blk >> 5, b = blk & 31;
    const int r0 = rg * 6;
    const int t = threadIdx.x;
    const int w = t >> 6, l = t & 63;
    const int l15 = l & 15, kgrp = l >> 4;

    if (t < 192) {
        int rr = t >> 5, c4 = (t & 31) * 4;
        *(float4*)(hrL + rr * DM + c4) = *(const float4*)(hr + ((size_t)(b * LN + r0 + rr)) * DM + c4);
    }
    s16x8 fh[4], fl4[4];
#pragma unroll
    for (int ks = 0; ks < 4; ++ks) {
        fh[ks]  = *(const s16x8*)(wfh + (size_t)(ks * 64 + l) * 8);
        fl4[ks] = *(const s16x8*)(wfl + (size_t)(ks * 64 + l) * 8);
    }
    float fbv = (l15 < 6) ? fb2[l15] : 0.f;
    __syncthreads();

    const float* hsB = hs + (size_t)(b * LN) * DM;
    for (int pr = 0; pr < 3; ++pr) {
        const int rA = r0 + pr * 2, rB = rA + 1;
        // build both tiles: 3072 tasks; 6 chunks of 2 reps with hoisted global loads
#pragma unroll
        for (int ch = 0; ch < 6; ++ch) {
            float4 h0[2], h1[2];
            int rrs[2], c0s[2], tts[2];
#pragma unroll
            for (int k = 0; k < 2; ++k) {
                int task = t + (ch * 2 + k) * 256;   // 0..3071
                int tt = task >= 1536;
                int rem = task - tt * 1536;
                int rr = rem >> 4, c0 = (rem & 15) * 8;
                rrs[k] = rr; c0s[k] = c0; tts[k] = tt;
                if (rr < EPN) {
                    int r = tt ? rB : rA;
                    int j = rr + (rr >= r);
                    const float* hp = hsB + (size_t)j * DM + c0;
                    h0[k] = *(const float4*)hp;
                    h1[k] = *(const float4*)(hp + 4);
                }
            }
#pragma unroll
            for (int k = 0; k < 2; ++k) {
                int rr = rrs[k], c0 = c0s[k], tt = tts[k];
                int swz = (rr & 7) << 4;
                uint4 pk = make_uint4(0, 0, 0, 0);
                if (rr < EPN) {
                    const float* rp = hrL + (pr * 2 + tt) * DM + c0;
                    f32x4 v0 = *(const f32x4*)rp, v1 = *(const f32x4*)(rp + 4);
                    float e0 = eluf(h0[k].x + v0[0]), e1 = eluf(h0[k].y + v0[1]);
                    float e2 = eluf(h0[k].z + v0[2]), e3 = eluf(h0[k].w + v0[3]);
                    float e4 = eluf(h1[k].x + v1[0]), e5 = eluf(h1[k].y + v1[1]);
                    float e6 = eluf(h1[k].z + v1[2]), e7 = eluf(h1[k].w + v1[3]);
                    pk.x = cvtpk(e0, e1); pk.y = cvtpk(e2, e3);
                    pk.z = cvtpk(e4, e5); pk.w = cvtpk(e6, e7);
                }
                *(uint4*)((tt ? tB : tA) + ((rr * 256 + c0 * 2) ^ swz)) = pk;
            }
        }
        __syncthreads();
        // 12 (tile, mt) MFMA tasks over 4 waves
        for (int q = w; q < 12; q += 4) {
            int tt = q >= 6;
            int mt = q - tt * 6;
            const char* tile = tt ? tB : tA;
            int r = tt ? rB : rA;
            int arow = mt * 16 + l15;
            const char* rb = tile + arow * 256;
            int swz = (arow & 7) << 4;
            s16x8 a[4];
#pragma unroll
            for (int ks = 0; ks < 4; ++ks)
                a[ks] = *(const s16x8*)(rb + (((ks * 32 + kgrp * 8) * 2) ^ swz));
            f32x4 acc = (f32x4){fbv, fbv, fbv, fbv};
#pragma unroll
            for (int ks = 0; ks < 4; ++ks)
                acc = __builtin_amdgcn_mfma_f32_16x16x32_bf16(a[ks], fh[ks], acc, 0, 0, 0);
#pragma unroll
            for (int ks = 0; ks < 4; ++ks)
                acc = __builtin_amdgcn_mfma_f32_16x16x32_bf16(a[ks], fl4[ks], acc, 0, 0, 0);
            if (l15 < 6) {
                float* ob = out + ((size_t)b * (LN * EPN) + (size_t)r * EPN) * 6;
#pragma unroll
                for (int i = 0; i < 4; ++i) {
                    int row = mt * 16 + kgrp * 4 + i;
                    if (row < EPN) ob[(size_t)row * 6 + l15] = acc[i];
                }
            }
        }
        __syncthreads();
    }
}

extern "C" void kernel_launch(void* const* d_in, const int* in_sizes, int n_in,
                              void* d_out, int out_size, void* d_ws, size_t ws_size,
                              hipStream_t stream) {
    const float* inputs = (const float*)d_in[0];
    const float* W0a = (const float*)d_in[3];
    const float* b0a = (const float*)d_in[4];
    const float* W0b = (const float*)d_in[5];
    const float* b0b = (const float*)d_in[6];
    const float* eW1 = (const float*)d_in[7];
    const float* eb1 = (const float*)d_in[8];
    const float* eW2 = (const float*)d_in[9];
    const float* eb2 = (const float*)d_in[10];
    const float* nW1 = (const float*)d_in[11];
    const float* nb1 = (const float*)d_in[12];
    const float* nW2 = (const float*)d_in[13];
    const float* nb2 = (const float*)d_in[14];
    const float* fW1 = (const float*)d_in[15];
    const float* fb1 = (const float*)d_in[16];
    const float* fW2 = (const float*)d_in[17];
    const float* fb2 = (const float*)d_in[18];
    float* out = (float*)d_out;

    const int NR = BN * LN;                                 // 3072 node rows
    unsigned short* whi = (unsigned short*)d_ws;            // 19 x 16384 bf16 hi
    unsigned short* wlo = whi + 19 * 16384;                 // 19 x 16384 bf16 lo
    float* hsA = (float*)(wlo + 19 * 16384);
    float* hrA = hsA + NR * DM;
    float* hsB = hrA + NR * DM;
    float* hrB = hsB + NR * DM;

    SrcTab tab;
    tab.p[0] = eW2;          tab.p[1] = eW2 + 16384;  tab.p[2] = eW2 + 32768;
    tab.p[3] = W0b;
    tab.p[4] = eW1;          tab.p[5] = eW1 + 16384;
    tab.p[6] = nW1;          tab.p[7] = nW2;          tab.p[8] = eW1 + 32768;  tab.p[9]  = eW1 + 49152;
    tab.p[10] = nW1 + 16384; tab.p[11] = nW2 + 16384; tab.p[12] = eW1 + 65536; tab.p[13] = eW1 + 81920;
    tab.p[14] = nW1 + 32768; tab.p[15] = nW2 + 32768; tab.p[16] = fW1;         tab.p[17] = fW1 + 16384;
    tab.p[18] = fW2;

    #define WM(m) (whi + (m) * 16384), (wlo + (m) * 16384)

    conv_pack_kernel<<<152, 256, 0, stream>>>(tab, whi, wlo);
    node0_kernel<<<192, 256, 0, stream>>>(inputs, W0a, b0a, WM(3), b0b, WM(4), WM(5), eb1, hsA, hrA);
    edge_node_kernel<<<512, 256, 0, stream>>>(hsA, hrA, whi, wlo, 0, eb2,
                                              6, 7, 8, nb1, nb2, eb1 + DM, hsB, hrB);
    edge_node_kernel<<<512, 256, 0, stream>>>(hsB, hrB, whi, wlo, 1, eb2 + DM,
                                              10, 11, 12, nb1 + DM, nb2 + DM, eb1 + 2 * DM, hsA, hrA);
    edge_node_kernel<<<512, 256, 0, stream>>>(hsA, hrA, whi, wlo, 2, eb2 + 2 * DM,
                                              14, 15, 16, nb1 + 2 * DM, nb2 + 2 * DM, fb1, hsB, hrB);
    final_kernel<<<512, 256, 0, stream>>>(hsB, hrB, WM(18), fb2, out);
    #undef WM
}

// Round 12
// 117.036 us; speedup vs baseline: 2.5583x; 1.0692x over previous
//
#include <hip/hip_runtime.h>
#include <hip/hip_bf16.h>

#define LN 96
#define BN 32
#define DM 128
#define EPN 95   // edges per receiver = L-1

typedef __attribute__((ext_vector_type(8))) short s16x8;
typedef __attribute__((ext_vector_type(4))) float f32x4;

__device__ __forceinline__ float eluf(float x){ return x > 0.f ? x : __expf(x) - 1.f; }
__device__ __forceinline__ unsigned short f2bf(float f){
    unsigned u = __float_as_uint(f);
    return (unsigned short)((u + 0x7fff + ((u >> 16) & 1)) >> 16);
}
__device__ __forceinline__ float bf2f(unsigned short h){ return __uint_as_float(((unsigned)h) << 16); }
// packed RNE f32->bf16 pair (1 instruction): D[15:0]=bf16(lo), D[31:16]=bf16(hi)
__device__ __forceinline__ unsigned cvtpk(float lo, float hi){
    unsigned r;
    asm("v_cvt_pk_bf16_f32 %0, %1, %2" : "=v"(r) : "v"(lo), "v"(hi));
    return r;
}

// ---------------- weight pack: 19 slots, fragment-order bf16 hi+lo ----------------
// chunk c=(nt*4+ks)*64+lane holds 8 elems: n = nt*16+(lane&15), k = ks*32+(lane>>4)*8+e
// slots: 0..2 eW2[i]; 3 W0b; 4,5 eW1[0] S/R; 6 nW1[0]; 7 nW2[0]; 8,9 eW1[1] S/R;
//        10 nW1[1]; 11 nW2[1]; 12,13 eW1[2] S/R; 14 nW1[2]; 15 nW2[2]; 16,17 fW1 S/R;
//        18 fW2 (128x6 zero-padded to 128x16)
struct SrcTab { const float* p[19]; };

__global__ void conv_pack_kernel(SrcTab tab, unsigned short* __restrict__ hi,
                                 unsigned short* __restrict__ lo){
    int tid = blockIdx.x * 256 + threadIdx.x;   // 19*2048 = 38912
    int m = tid >> 11, c = tid & 2047;
    int l = c & 63, f = c >> 6;
    int n = (f >> 2) * 16 + (l & 15);
    int k0 = (f & 3) * 32 + (l >> 4) * 8;
    union { unsigned short us[8]; uint4 v; } ph, pl;
#pragma unroll
    for (int e = 0; e < 8; ++e){
        float x;
        if (m == 18) x = (n < 6) ? tab.p[18][(k0 + e) * 6 + n] : 0.f;
        else         x = tab.p[m][(k0 + e) * DM + n];
        unsigned short h = f2bf(x);
        ph.us[e] = h;
        pl.us[e] = f2bf(x - bf2f(h));
    }
    *(uint4*)(hi + (size_t)tid * 8) = ph.v;
    *(uint4*)(lo + (size_t)tid * 8) = pl.v;
}

// ---------------- wave-level 16x32 matmul step (2 n-tiles per wave, hi+lo) ----------------
__device__ __forceinline__ void mmw(const char* atile, int l,
                                    const unsigned short* __restrict__ whW,
                                    const unsigned short* __restrict__ wlW,
                                    f32x4 acc[2]) {
    const int l15 = l & 15, kgrp = l >> 4;
    s16x8 a[4];
#pragma unroll
    for (int ks = 0; ks < 4; ++ks)
        a[ks] = *(const s16x8*)(atile + ((l15 * 256 + (ks * 32 + kgrp * 8) * 2) ^ ((l15 & 7) << 4)));
#pragma unroll
    for (int ntl = 0; ntl < 2; ++ntl) {
#pragma unroll
        for (int ks = 0; ks < 4; ++ks) {
            s16x8 bh = *(const s16x8*)(whW + (size_t)((ntl * 4 + ks) * 64 + l) * 8);
            acc[ntl] = __builtin_amdgcn_mfma_f32_16x16x32_bf16(a[ks], bh, acc[ntl], 0, 0, 0);
        }
#pragma unroll
        for (int ks = 0; ks < 4; ++ks) {
            s16x8 bl = *(const s16x8*)(wlW + (size_t)((ntl * 4 + ks) * 64 + l) * 8);
            acc[ntl] = __builtin_amdgcn_mfma_f32_16x16x32_bf16(a[ks], bl, acc[ntl], 0, 0, 0);
        }
    }
}

__device__ __forceinline__ void store_act(char* atile, int l, int w, f32x4 acc[2]) {
    const int l15 = l & 15, kgrp = l >> 4;
#pragma unroll
    for (int ntl = 0; ntl < 2; ++ntl)
#pragma unroll
        for (int i = 0; i < 4; ++i) {
            int row = kgrp * 4 + i;              // C/D: col=lane&15, row=(lane>>4)*4+i
            int col = (2 * w + ntl) * 16 + l15;
            *(unsigned short*)(atile + ((row * 256 + col * 2) ^ ((row & 7) << 4))) = f2bf(eluf(acc[ntl][i]));
        }
}

// ---------------- node0: input MLP (scalar W0a, MFMA W0b) + proj eW1[0] ----------------
// 192 blocks x 256 thr; 16 rows/block; XCD-aligned: blk = q*32 + b (batch in low 5 bits)
__global__ __launch_bounds__(256) void node0_kernel(
    const float* __restrict__ in,
    const float* __restrict__ W0a, const float* __restrict__ b0a,
    const unsigned short* __restrict__ w2h, const unsigned short* __restrict__ w2l,
    const float* __restrict__ b2,
    const unsigned short* __restrict__ wsh, const unsigned short* __restrict__ wsl,
    const unsigned short* __restrict__ wrh, const unsigned short* __restrict__ wrl,
    const float* __restrict__ bp,
    float* __restrict__ hs, float* __restrict__ hr) {
    __shared__ char atile[16 * 256];
    const int t = threadIdx.x;
    const int q = blockIdx.x >> 5, bblk = blockIdx.x & 31;
    const int row0 = bblk * LN + q * 16;
    const int l = t & 63, w = t >> 6;
    const int l15 = l & 15, kgrp = l >> 4;

    {   // fused scalar K=4 layer (W0a) -> bf16 tile
        int rr = t >> 4, qq = t & 15, c0 = qq * 8;
        int swz = (rr & 7) << 4;
        union { unsigned short us[8]; uint4 v; } pk;
        int row = row0 + rr;
        int b = row / LN, ll = row - b * LN;
        float4 x = *(const float4*)(in + (size_t)(ll * BN + b) * 4);
#pragma unroll
        for (int j = 0; j < 8; ++j) {
            int cc = c0 + j;
            float a = b0a[cc] + x.x * W0a[cc] + x.y * W0a[DM + cc]
                    + x.z * W0a[2 * DM + cc] + x.w * W0a[3 * DM + cc];
            pk.us[j] = f2bf(eluf(a));
        }
        *(uint4*)(atile + ((rr * 256 + c0 * 2) ^ swz)) = pk.v;
    }
    __syncthreads();

    f32x4 acc[2];
    const int cA = (2 * w) * 16 + l15, cB = (2 * w + 1) * 16 + l15;
    {   // layer W0b
        float ba = b2[cA], bb = b2[cB];
        acc[0] = (f32x4){ba, ba, ba, ba};
        acc[1] = (f32x4){bb, bb, bb, bb};
        mmw(atile, l, w2h + w * 4096, w2l + w * 4096, acc);
        __syncthreads();
        store_act(atile, l, w, acc);
        __syncthreads();
    }
    // projection S
    acc[0] = (f32x4){0.f, 0.f, 0.f, 0.f};
    acc[1] = (f32x4){0.f, 0.f, 0.f, 0.f};
    mmw(atile, l, wsh + w * 4096, wsl + w * 4096, acc);
#pragma unroll
    for (int ntl = 0; ntl < 2; ++ntl)
#pragma unroll
        for (int i = 0; i < 4; ++i)
            hs[(size_t)(row0 + kgrp * 4 + i) * DM + (2 * w + ntl) * 16 + l15] = acc[ntl][i];
    // projection R (+bp)
    {
        float ba = bp[cA], bb = bp[cB];
        acc[0] = (f32x4){ba, ba, ba, ba};
        acc[1] = (f32x4){bb, bb, bb, bb};
        mmw(atile, l, wrh + w * 4096, wrl + w * 4096, acc);
    }
#pragma unroll
    for (int ntl = 0; ntl < 2; ++ntl)
#pragma unroll
        for (int i = 0; i < 4; ++i)
            hr[(size_t)(row0 + kgrp * 4 + i) * DM + (2 * w + ntl) * 16 + l15] = acc[ntl][i];
}

// ---------------- fused edge+node: 512 blocks x 256 thr; block owns 6 receivers (3 pairs) ------
// XCD-aligned: blk = rg*32 + b -> blk%8 = b%8. hs buffers carry one pad row (row 3072) so the
// y1 build is branch-free: row 95's A-tile content is garbage but only feeds masked C-row 95.
__global__ __launch_bounds__(256) void edge_node_kernel(
    const float* __restrict__ hsIn, const float* __restrict__ hrIn,
    const unsigned short* __restrict__ whi, const unsigned short* __restrict__ wlo,
    int eslot, const float* __restrict__ eb2v,
    int s1, int s2, int sS,
    const float* __restrict__ b1, const float* __restrict__ b2, const float* __restrict__ bp,
    float* __restrict__ hsOut, float* __restrict__ hrOut) {
    __shared__ char tileA[LN * 256];  // 96x128 bf16, XOR-swizzled
    __shared__ char tileB[LN * 256];
    __shared__ float hrL[6 * DM];
    __shared__ float gL[6 * DM];
    __shared__ char actA[16 * 256];
    __shared__ char actB[16 * 256];
    const int blk = blockIdx.x;
    const int rg = blk >> 5, b = blk & 31;
    const int r0 = rg * 6;
    const int t = threadIdx.x;
    const int w = t >> 6, l = t & 63;
    const int l15 = l & 15, kgrp = l >> 4;

    if (t < 192) {
        int rr = t >> 5, c4 = (t & 31) * 4;
        *(float4*)(hrL + rr * DM + c4) = *(const float4*)(hrIn + ((size_t)(b * LN + r0 + rr)) * DM + c4);
    }
    // edge B-frags (hi only), wave n-split
    s16x8 bfr[2][4];
#pragma unroll
    for (int ntl = 0; ntl < 2; ++ntl)
#pragma unroll
        for (int ks = 0; ks < 4; ++ks)
            bfr[ntl][ks] = *(const s16x8*)(whi + (size_t)eslot * 16384 +
                           (size_t)(((2 * w + ntl) * 4 + ks) * 64 + l) * 8);
    float b20 = eb2v[(2 * w) * 16 + l15], b21 = eb2v[(2 * w + 1) * 16 + l15];
    __syncthreads();

    const float* hsBase = hsIn + (size_t)(b * LN) * DM;
    for (int pr = 0; pr < 3; ++pr) {
        const int rA = r0 + pr * 2, rB = rA + 1;
        // build BOTH y1 tiles: 3072 tasks, branch-free; 6 chunks of 2 with hoisted loads
#pragma unroll
        for (int ch = 0; ch < 6; ++ch) {
            float4 h0[2], h1[2];
            int rrs[2], c0s[2], tts[2];
#pragma unroll
            for (int k = 0; k < 2; ++k) {
                int task = t + (ch * 2 + k) * 256;   // 0..3071
                int tt = task >= 1536;
                int rem = task - tt * 1536;
                int rr = rem >> 4, c0 = (rem & 15) * 8;
                rrs[k] = rr; c0s[k] = c0; tts[k] = tt;
                int r = tt ? rB : rA;
                int j = rr + (rr >= r);              // rr==95 -> j==96 (pad row, masked later)
                const float* hp = hsBase + (size_t)j * DM + c0;
                h0[k] = *(const float4*)hp;
                h1[k] = *(const float4*)(hp + 4);
            }
#pragma unroll
            for (int k = 0; k < 2; ++k) {
                int rr = rrs[k], c0 = c0s[k], tt = tts[k];
                const float* rp = hrL + (pr * 2 + tt) * DM + c0;
                f32x4 v0 = *(const f32x4*)rp, v1 = *(const f32x4*)(rp + 4);
                float e0 = eluf(h0[k].x + v0[0]), e1 = eluf(h0[k].y + v0[1]);
                float e2 = eluf(h0[k].z + v0[2]), e3 = eluf(h0[k].w + v0[3]);
                float e4 = eluf(h1[k].x + v1[0]), e5 = eluf(h1[k].y + v1[1]);
                float e6 = eluf(h1[k].z + v1[2]), e7 = eluf(h1[k].w + v1[3]);
                uint4 pk;
                pk.x = cvtpk(e0, e1); pk.y = cvtpk(e2, e3);
                pk.z = cvtpk(e4, e5); pk.w = cvtpk(e6, e7);
                *(uint4*)((tt ? tileB : tileA) + ((rr * 256 + c0 * 2) ^ ((rr & 7) << 4))) = pk;
            }
        }
        __syncthreads();
        // MFMA + epilogue for both tiles (n-split: wave owns 32 cols)
#pragma unroll
        for (int slot = 0; slot < 2; ++slot) {
            const char* tile = slot ? tileB : tileA;
            f32x4 acc[6][2] = {};
#pragma unroll
            for (int mt = 0; mt < 6; ++mt) {
                int arow = mt * 16 + l15;
                const char* rb = tile + arow * 256;
                int swz = (arow & 7) << 4;
#pragma unroll
                for (int ks = 0; ks < 4; ++ks) {
                    s16x8 a = *(const s16x8*)(rb + (((ks * 32 + kgrp * 8) * 2) ^ swz));
                    acc[mt][0] = __builtin_amdgcn_mfma_f32_16x16x32_bf16(a, bfr[0][ks], acc[mt][0], 0, 0, 0);
                    acc[mt][1] = __builtin_amdgcn_mfma_f32_16x16x32_bf16(a, bfr[1][ks], acc[mt][1], 0, 0, 0);
                }
            }
            float cs0 = 0.f, cs1 = 0.f;
#pragma unroll
            for (int mt = 0; mt < 6; ++mt)
#pragma unroll
                for (int i = 0; i < 4; ++i) {
                    int row = mt * 16 + kgrp * 4 + i;
                    if (row < EPN) {
                        cs0 += eluf(acc[mt][0][i] + b20);
                        cs1 += eluf(acc[mt][1][i] + b21);
                    }
                }
            cs0 += __shfl_xor(cs0, 16); cs0 += __shfl_xor(cs0, 32);
            cs1 += __shfl_xor(cs1, 16); cs1 += __shfl_xor(cs1, 32);
            if (l < 16) {
                gL[(pr * 2 + slot) * DM + (2 * w) * 16 + l]     = cs0 * (1.f / 95.f);
                gL[(pr * 2 + slot) * DM + (2 * w + 1) * 16 + l] = cs1 * (1.f / 95.f);
            }
        }
        __syncthreads();
    }

    // ---------- node tail on the 6 g rows ----------
    {
        int rr = t >> 4, q = t & 15, c0 = q * 8;
        int swz = (rr & 7) << 4;
        union { unsigned short us[8]; uint4 v; } pk;
        if (rr < 6) {
            const float* src = gL + rr * DM + c0;
            float4 f0 = *(const float4*)(src);
            float4 f1 = *(const float4*)(src + 4);
            pk.us[0] = f2bf(f0.x); pk.us[1] = f2bf(f0.y); pk.us[2] = f2bf(f0.z); pk.us[3] = f2bf(f0.w);
            pk.us[4] = f2bf(f1.x); pk.us[5] = f2bf(f1.y); pk.us[6] = f2bf(f1.z); pk.us[7] = f2bf(f1.w);
        } else pk.v = make_uint4(0, 0, 0, 0);
        *(uint4*)(actA + ((rr * 256 + c0 * 2) ^ swz)) = pk.v;
    }
    __syncthreads();

    f32x4 acc[2];
    const int cA = (2 * w) * 16 + l15, cB = (2 * w + 1) * 16 + l15;
    {   // layer 1
        float ba = b1[cA], bb = b1[cB];
        acc[0] = (f32x4){ba, ba, ba, ba};
        acc[1] = (f32x4){bb, bb, bb, bb};
        mmw(actA, l, whi + (size_t)s1 * 16384 + w * 4096, wlo + (size_t)s1 * 16384 + w * 4096, acc);
        __syncthreads();
        store_act(actB, l, w, acc);
        __syncthreads();
    }
    {   // layer 2
        float ba = b2[cA], bb = b2[cB];
        acc[0] = (f32x4){ba, ba, ba, ba};
        acc[1] = (f32x4){bb, bb, bb, bb};
        mmw(actB, l, whi + (size_t)s2 * 16384 + w * 4096, wlo + (size_t)s2 * 16384 + w * 4096, acc);
        __syncthreads();
        store_act(actA, l, w, acc);
        __syncthreads();
    }
    // projection S
    acc[0] = (f32x4){0.f, 0.f, 0.f, 0.f};
    acc[1] = (f32x4){0.f, 0.f, 0.f, 0.f};
    mmw(actA, l, whi + (size_t)sS * 16384 + w * 4096, wlo + (size_t)sS * 16384 + w * 4096, acc);
#pragma unroll
    for (int ntl = 0; ntl < 2; ++ntl)
#pragma unroll
        for (int i = 0; i < 4; ++i) {
            int row = kgrp * 4 + i;
            if (row < 6)
                hsOut[(size_t)(b * LN + r0 + row) * DM + (2 * w + ntl) * 16 + l15] = acc[ntl][i];
        }
    // projection R (+bp)
    {
        float ba = bp[cA], bb = bp[cB];
        acc[0] = (f32x4){ba, ba, ba, ba};
        acc[1] = (f32x4){bb, bb, bb, bb};
        mmw(actA, l, whi + (size_t)(sS + 1) * 16384 + w * 4096, wlo + (size_t)(sS + 1) * 16384 + w * 4096, acc);
    }
#pragma unroll
    for (int ntl = 0; ntl < 2; ++ntl)
#pragma unroll
        for (int i = 0; i < 4; ++i) {
            int row = kgrp * 4 + i;
            if (row < 6)
                hrOut[(size_t)(b * LN + r0 + row) * DM + (2 * w + ntl) * 16 + l15] = acc[ntl][i];
        }
}

// ---------------- final (MFMA): 512 blocks x 256 thr; block owns 6 receivers (3 pairs) --------
__global__ __launch_bounds__(256) void final_kernel(
    const float* __restrict__ hs, const float* __restrict__ hr,
    const unsigned short* __restrict__ wfh, const unsigned short* __restrict__ wfl,
    const float* __restrict__ fb2, float* __restrict__ out) {
    __shared__ char tA[LN * 256];
    __shared__ char tB[LN * 256];
    __shared__ float hrL[6 * DM];
    const int blk = blockIdx.x;
    const int rg = blk >> 5, b = blk & 31;
    const int r0 = rg * 6;
    const int t = threadIdx.x;
    const int w = t >> 6, l = t & 63;
    const int l15 = l & 15, kgrp = l >> 4;

    if (t < 192) {
        int rr = t >> 5, c4 = (t & 31) * 4;
        *(float4*)(hrL + rr * DM + c4) = *(const float4*)(hr + ((size_t)(b * LN + r0 + rr)) * DM + c4);
    }
    s16x8 fh[4], fl4[4];
#pragma unroll
    for (int ks = 0; ks < 4; ++ks) {
        fh[ks]  = *(const s16x8*)(wfh + (size_t)(ks * 64 + l) * 8);
        fl4[ks] = *(const s16x8*)(wfl + (size_t)(ks * 64 + l) * 8);
    }
    float fbv = (l15 < 6) ? fb2[l15] : 0.f;
    __syncthreads();

    const float* hsBase = hs + (size_t)(b * LN) * DM;
    for (int pr = 0; pr < 3; ++pr) {
        const int rA = r0 + pr * 2, rB = rA + 1;
#pragma unroll
        for (int ch = 0; ch < 6; ++ch) {
            float4 h0[2], h1[2];
            int rrs[2], c0s[2], tts[2];
#pragma unroll
            for (int k = 0; k < 2; ++k) {
                int task = t + (ch * 2 + k) * 256;   // 0..3071
                int tt = task >= 1536;
                int rem = task - tt * 1536;
                int rr = rem >> 4, c0 = (rem & 15) * 8;
                rrs[k] = rr; c0s[k] = c0; tts[k] = tt;
                int r = tt ? rB : rA;
                int j = rr + (rr >= r);
                const float* hp = hsBase + (size_t)j * DM + c0;
                h0[k] = *(const float4*)hp;
                h1[k] = *(const float4*)(hp + 4);
            }
#pragma unroll
            for (int k = 0; k < 2; ++k) {
                int rr = rrs[k], c0 = c0s[k], tt = tts[k];
                const float* rp = hrL + (pr * 2 + tt) * DM + c0;
                f32x4 v0 = *(const f32x4*)rp, v1 = *(const f32x4*)(rp + 4);
                float e0 = eluf(h0[k].x + v0[0]), e1 = eluf(h0[k].y + v0[1]);
                float e2 = eluf(h0[k].z + v0[2]), e3 = eluf(h0[k].w + v0[3]);
                float e4 = eluf(h1[k].x + v1[0]), e5 = eluf(h1[k].y + v1[1]);
                float e6 = eluf(h1[k].z + v1[2]), e7 = eluf(h1[k].w + v1[3]);
                uint4 pk;
                pk.x = cvtpk(e0, e1); pk.y = cvtpk(e2, e3);
                pk.z = cvtpk(e4, e5); pk.w = cvtpk(e6, e7);
                *(uint4*)((tt ? tB : tA) + ((rr * 256 + c0 * 2) ^ ((rr & 7) << 4))) = pk;
            }
        }
        __syncthreads();
        // 12 (tile, mt) MFMA tasks over 4 waves
        for (int q = w; q < 12; q += 4) {
            int tt = q >= 6;
            int mt = q - tt * 6;
            const char* tile = tt ? tB : tA;
            int r = tt ? rB : rA;
            int arow = mt * 16 + l15;
            const char* rb = tile + arow * 256;
            int swz = (arow & 7) << 4;
            s16x8 a[4];
#pragma unroll
            for (int ks = 0; ks < 4; ++ks)
                a[ks] = *(const s16x8*)(rb + (((ks * 32 + kgrp * 8) * 2) ^ swz));
            f32x4 acc = (f32x4){fbv, fbv, fbv, fbv};
#pragma unroll
            for (int ks = 0; ks < 4; ++ks)
                acc = __builtin_amdgcn_mfma_f32_16x16x32_bf16(a[ks], fh[ks], acc, 0, 0, 0);
#pragma unroll
            for (int ks = 0; ks < 4; ++ks)
                acc = __builtin_amdgcn_mfma_f32_16x16x32_bf16(a[ks], fl4[ks], acc, 0, 0, 0);
            if (l15 < 6) {
                float* ob = out + ((size_t)b * (LN * EPN) + (size_t)r * EPN) * 6;
#pragma unroll
                for (int i = 0; i < 4; ++i) {
                    int row = mt * 16 + kgrp * 4 + i;
                    if (row < EPN) ob[(size_t)row * 6 + l15] = acc[i];
                }
            }
        }
        __syncthreads();
    }
}

extern "C" void kernel_launch(void* const* d_in, const int* in_sizes, int n_in,
                              void* d_out, int out_size, void* d_ws, size_t ws_size,
                              hipStream_t stream) {
    const float* inputs = (const float*)d_in[0];
    const float* W0a = (const float*)d_in[3];
    const float* b0a = (const float*)d_in[4];
    const float* W0b = (const float*)d_in[5];
    const float* b0b = (const float*)d_in[6];
    const float* eW1 = (const float*)d_in[7];
    const float* eb1 = (const float*)d_in[8];
    const float* eW2 = (const float*)d_in[9];
    const float* eb2 = (const float*)d_in[10];
    const float* nW1 = (const float*)d_in[11];
    const float* nb1 = (const float*)d_in[12];
    const float* nW2 = (const float*)d_in[13];
    const float* nb2 = (const float*)d_in[14];
    const float* fW1 = (const float*)d_in[15];
    const float* fb1 = (const float*)d_in[16];
    const float* fW2 = (const float*)d_in[17];
    const float* fb2 = (const float*)d_in[18];
    float* out = (float*)d_out;

    const int NR = BN * LN;                                 // 3072 node rows (+1 pad row for hs)
    unsigned short* whi = (unsigned short*)d_ws;            // 19 x 16384 bf16 hi
    unsigned short* wlo = whi + 19 * 16384;                 // 19 x 16384 bf16 lo
    float* hsA = (float*)(wlo + 19 * 16384);                // (NR+1) x DM
    float* hrA = hsA + (NR + 1) * DM;                       // NR x DM
    float* hsB = hrA + NR * DM;                             // (NR+1) x DM
    float* hrB = hsB + (NR + 1) * DM;                       // NR x DM

    SrcTab tab;
    tab.p[0] = eW2;          tab.p[1] = eW2 + 16384;  tab.p[2] = eW2 + 32768;
    tab.p[3] = W0b;
    tab.p[4] = eW1;          tab.p[5] = eW1 + 16384;
    tab.p[6] = nW1;          tab.p[7] = nW2;          tab.p[8] = eW1 + 32768;  tab.p[9]  = eW1 + 49152;
    tab.p[10] = nW1 + 16384; tab.p[11] = nW2 + 16384; tab.p[12] = eW1 + 65536; tab.p[13] = eW1 + 81920;
    tab.p[14] = nW1 + 32768; tab.p[15] = nW2 + 32768; tab.p[16] = fW1;         tab.p[17] = fW1 + 16384;
    tab.p[18] = fW2;

    #define WM(m) (whi + (m) * 16384), (wlo + (m) * 16384)

    conv_pack_kernel<<<152, 256, 0, stream>>>(tab, whi, wlo);
    node0_kernel<<<192, 256, 0, stream>>>(inputs, W0a, b0a, WM(3), b0b, WM(4), WM(5), eb1, hsA, hrA);
    edge_node_kernel<<<512, 256, 0, stream>>>(hsA, hrA, whi, wlo, 0, eb2,
                                              6, 7, 8, nb1, nb2, eb1 + DM, hsB, hrB);
    edge_node_kernel<<<512, 256, 0, stream>>>(hsB, hrB, whi, wlo, 1, eb2 + DM,
                                              10, 11, 12, nb1 + DM, nb2 + DM, eb1 + 2 * DM, hsA, hrA);
    edge_node_kernel<<<512, 256, 0, stream>>>(hsA, hrA, whi, wlo, 2, eb2 + 2 * DM,
                                              14, 15, 16, nb1 + 2 * DM, nb2 + 2 * DM, fb1, hsB, hrB);
    final_kernel<<<512, 256, 0, stream>>>(hsB, hrB, WM(18), fb2, out);
    #undef WM
}